// Round 8
// baseline (3478.762 us; speedup 1.0000x reference)
//
#include <hip/hip_runtime.h>

#define B_ 512
#define S_ 256
#define V_ 128
#define E_ 64
#define H_ 128
#define NT_ 512

// ---------------- dtype sniff: first 512 bytes of one_hot_inputs ----------------
// f32: 512B = row 0 (one 1.0f) -> 1 nonzero u16; bf16: rows 0+1 -> 2 nonzero u16
__global__ void k_sniff(const unsigned short* oh, int* flag){
  if (threadIdx.x == 0){
    int cnt = 0;
    for (int i = 0; i < 256; ++i) cnt += (oh[i] != 0);
    *flag = (cnt == 1) ? 1 : 0;
  }
}

__device__ __forceinline__ float ldf(const void* p, long i, int isf){
  if (isf) return ((const float*)p)[i];
  unsigned v = ((const unsigned short*)p)[i];
  union{unsigned u; float f;} c; c.u = v << 16; return c.f;
}

__global__ void k_cvt(const void* src, float* dst, int n, const int* flag){
  int i = blockIdx.x*blockDim.x + threadIdx.x;
  if (i < n) dst[i] = ldf(src, i, *flag);
}

// ---------------- lens: mask dtype sniffed (u8 / i32 / bf16 / f32) ----------------
__global__ void k_lens(const void* maskp, int* lens){
  int b = blockIdx.x*blockDim.x + threadIdx.x;
  if (b >= B_) return;
  const unsigned char* mc = (const unsigned char*)maskp;
  int mode;
  if (mc[0] == 1 && mc[1] == 1) mode = 0;
  else if (mc[0] == 1)          mode = 1;
  else if (mc[0] == 0x80)       mode = 2;
  else                          mode = 3;
  int cnt = 0;
  for (int j = 0; j < S_; ++j){
    long idx = (long)b*S_ + j; int v;
    if (mode == 0)      v = (mc[idx] != 0);
    else if (mode == 1) v = (((const int*)maskp)[idx] != 0);
    else if (mode == 2) v = (((const unsigned short*)maskp)[idx] != 0);
    else                v = (((const float*)maskp)[idx] > 0.5f);
    cnt += v;
  }
  lens[b] = cnt;
}

// ---------------- one-hot -> token index (dtype-adaptive) ----------------
__global__ void k_ids(const void* ohin, const void* ohout, const int* flag,
                      int* __restrict__ idsIn, int* __restrict__ idsOut){
  int row = blockIdx.x*blockDim.x + threadIdx.x;
  if (row >= B_*S_) return;
  long base = (long)row * V_;
  int isf = *flag;
  int ia = 0, ib = 0;
  if (isf){
    const float* a = (const float*)ohin; const float* c = (const float*)ohout;
    for (int v = 0; v < V_; ++v){
      if (a[base+v] > 0.5f) ia = v;
      if (c[base+v] > 0.5f) ib = v;
    }
  } else {
    const unsigned short* a = (const unsigned short*)ohin;
    const unsigned short* c = (const unsigned short*)ohout;
    for (int v = 0; v < V_; ++v){
      if (a[base+v] >= 0x3F00u) ia = v;
      if (c[base+v] >= 0x3F00u) ib = v;
    }
  }
  idsIn[row] = ia; idsOut[row] = ib;
}

// ---------------- fold embedding + input projection + biases into [V][H] tables ----------------
__global__ void k_tables(const void* W_emb, const void* b_emb,
                         const void* W_ih_e, const void* b_ih_e, const void* b_hh_e,
                         const void* W_ih_d, const void* b_ih_d, const void* b_hh_d,
                         const int* flag,
                         float* __restrict__ encT, float* __restrict__ decT,
                         float* __restrict__ posT){
  int v = blockIdx.x, h = threadIdx.x;
  int isf = *flag;
  float ae = 0.f, ad = 0.f;
  for (int e = 0; e < E_; ++e){
    float x = ldf(W_emb, (long)e*V_ + v, isf) + ldf(b_emb, e, isf);
    ae = fmaf(ldf(W_ih_e, (long)h*(E_+V_) + e, isf), x, ae);
    ad = fmaf(ldf(W_ih_d, (long)h*E_ + e, isf), x, ad);
  }
  encT[v*H_ + h] = ae + ldf(b_ih_e, h, isf) + ldf(b_hh_e, h, isf);
  decT[v*H_ + h] = ad + ldf(b_ih_d, h, isf) + ldf(b_hh_d, h, isf);
  posT[v*H_ + h] = ldf(W_ih_e, (long)h*(E_+V_) + E_ + v, isf);
}

#define CADD(s, j) do{ ca.x=fmaf((s),cR4[j].x,ca.x); ca.y=fmaf((s),cR4[j].y,ca.y); \
                       ca.z=fmaf((s),cR4[j].z,ca.z); ca.w=fmaf((s),cR4[j].w,ca.w);}while(0)

// ---------------- main serial kernel: one workgroup per batch row, all f32 ----------------
// Stores dec_k (f32) directly into out[b][k][:] for k=1..255; k_logits transforms in place.
__global__ __launch_bounds__(NT_, 4) void k_main(
    const int* __restrict__ idsIn, const int* __restrict__ idsOut, const int* __restrict__ lens,
    const float* __restrict__ encT, const float* __restrict__ decT, const float* __restrict__ posT,
    const float* __restrict__ W_hh_e, const float* __restrict__ W_e2d, const float* __restrict__ b_e2d,
    const float* __restrict__ W_hh_d, float* __restrict__ out)
{
  __shared__ __align__(16) float hv0[H_], hv1[H_], nxtF[H_], decF[H_];
  __shared__ __align__(16) float scr[S_];
  __shared__ __align__(16) float4 ctxP4[16*32];
  __shared__ float red[4];

  const int b = blockIdx.x, t = threadIdx.x;
  const int h = t >> 2, q4 = t & 3;      // matvec: 4 threads / output row
  const int hq = t & 31, g = t >> 5;     // fragments: 32 h-quads x 16 s-groups
  const int len = lens[b];

  // out row 0: log(full(EPS).at[:,0].set(1))
  if (t < V_) out[(size_t)b*S_*V_ + t] = (t==0) ? 0.f : -46.051701859880914f;

  // encoder recurrent weights (XOR-staggered)
  float4 wq[8];
  #pragma unroll
  for (int r=0;r<8;++r) wq[r] = ((const float4*)W_hh_e)[h*32 + q4*8 + (r^q4)];

  float4 cR4[16];   // enc[s][hq*4..+3] for s = g*16+j  (single f32 copy, scores+ctx)
  #pragma unroll
  for (int j=0;j<16;++j) cR4[j] = make_float4(0.f,0.f,0.f,0.f);

  if (t < H_){ hv0[t]=0.f; hv1[t]=0.f; }
  __syncthreads();

  // -------- encoder: 1 barrier/step; fragment capture via uniform switch --------
  const int* idsInB = idsIn + b*S_;
  int cur = 0;
  for (int st=0; st<len; ++st){
    const float* hvc = cur ? hv1 : hv0;
    float* hvn = cur ? hv0 : hv1;
    const float4* hp = (const float4*)(hvc + q4*32);
    float a0=0.f, a1=0.f;
    #pragma unroll
    for (int r=0;r<8;r+=2){
      float4 u = hp[r^q4], v = hp[(r+1)^q4];
      a0 = fmaf(wq[r].x,u.x,a0);   a0 = fmaf(wq[r].y,u.y,a0);
      a0 = fmaf(wq[r].z,u.z,a0);   a0 = fmaf(wq[r].w,u.w,a0);
      a1 = fmaf(wq[r+1].x,v.x,a1); a1 = fmaf(wq[r+1].y,v.y,a1);
      a1 = fmaf(wq[r+1].z,v.z,a1); a1 = fmaf(wq[r+1].w,v.w,a1);
    }
    float acc = a0 + a1;
    acc += __shfl_xor(acc,1); acc += __shfl_xor(acc,2);
    if (q4==0){
      float pre = acc + encT[idsInB[st]*H_ + h];
      if (st < V_) pre += posT[st*H_ + h];
      hvn[h] = tanhf(pre);
    }
    __syncthreads();
    if (g == (st >> 4)){
      float4 v = ((const float4*)hvn)[hq];
      switch (st & 15){
        case 0:  cR4[0]=v;  break; case 1:  cR4[1]=v;  break;
        case 2:  cR4[2]=v;  break; case 3:  cR4[3]=v;  break;
        case 4:  cR4[4]=v;  break; case 5:  cR4[5]=v;  break;
        case 6:  cR4[6]=v;  break; case 7:  cR4[7]=v;  break;
        case 8:  cR4[8]=v;  break; case 9:  cR4[9]=v;  break;
        case 10: cR4[10]=v; break; case 11: cR4[11]=v; break;
        case 12: cR4[12]=v; break; case 13: cR4[13]=v; break;
        case 14: cR4[14]=v; break; case 15: cR4[15]=v; break;
      }
    }
    cur ^= 1;
  }
  const float* hvF = cur ? hv1 : hv0;
  { // frozen rows len..255 replicate the last state
    float4 vl = ((const float4*)hvF)[hq];
    #pragma unroll
    for (int j=0;j<16;++j) if (g*16 + j >= len) cR4[j] = vl;
  }

  // decoder recurrent weights overwrite wq (encoder weights dead)
  #pragma unroll
  for (int r=0;r<8;++r) wq[r] = ((const float4*)W_hh_d)[h*32 + q4*8 + (r^q4)];

  const int* idsOutB = idsOut + b*S_;

  // -------- decode loop (reference order; logits deferred to k_logits) --------
  for (int k=0; k<S_; ++k){
    // ---- P1: nxt ----
    if (k == 0){
      const float4* hp  = (const float4*)(hvF + q4*32);
      const float4* We4 = (const float4*)W_e2d + h*32 + q4*8;
      float a = 0.f;
      #pragma unroll
      for (int r=0;r<8;++r){ float4 u = hp[r]; float4 w = We4[r];
        a = fmaf(w.x,u.x,a); a = fmaf(w.y,u.y,a);
        a = fmaf(w.z,u.z,a); a = fmaf(w.w,u.w,a); }
      a += __shfl_xor(a,1); a += __shfl_xor(a,2);
      if (q4==0) nxtF[h] = a + b_e2d[h];
    } else {
      int id = idsOutB[k-1];
      const float4* dp = (const float4*)decF + q4*8;
      float a0=0.f, a1=0.f;
      #pragma unroll
      for (int r=0;r<8;r+=2){
        float4 u = dp[r^q4], v = dp[(r+1)^q4];
        a0 = fmaf(wq[r].x,u.x,a0);   a0 = fmaf(wq[r].y,u.y,a0);
        a0 = fmaf(wq[r].z,u.z,a0);   a0 = fmaf(wq[r].w,u.w,a0);
        a1 = fmaf(wq[r+1].x,v.x,a1); a1 = fmaf(wq[r+1].y,v.y,a1);
        a1 = fmaf(wq[r+1].z,v.z,a1); a1 = fmaf(wq[r+1].w,v.w,a1);
      }
      float acc = a0 + a1;
      acc += __shfl_xor(acc,1); acc += __shfl_xor(acc,2);
      if (q4==0) nxtF[h] = tanhf(acc + decT[id*H_ + h]);
    }
    __syncthreads();

    // ---- P2: scores via per-lane partials + half-wave reduce-scatter ----
    {
      float4 nx = ((const float4*)nxtF)[hq];
      float p[16];
      #pragma unroll
      for (int j=0;j<16;++j){
        float s =      cR4[j].x*nx.x;
        s = fmaf(cR4[j].y,nx.y,s); s = fmaf(cR4[j].z,nx.z,s); s = fmaf(cR4[j].w,nx.w,s);
        p[j] = s;
      }
      const int s1 = (hq>>4)&1, s2=(hq>>3)&1, s3=(hq>>2)&1, s4=(hq>>1)&1;
      float x[8];
      #pragma unroll
      for (int i=0;i<8;++i){
        float keep = s1 ? p[i+8] : p[i];
        float send = s1 ? p[i]   : p[i+8];
        x[i] = keep + __shfl_xor(send, 16);
      }
      float y[4];
      #pragma unroll
      for (int i=0;i<4;++i){
        float keep = s2 ? x[i+4] : x[i];
        float send = s2 ? x[i]   : x[i+4];
        y[i] = keep + __shfl_xor(send, 8);
      }
      float z[2];
      #pragma unroll
      for (int i=0;i<2;++i){
        float keep = s3 ? y[i+2] : y[i];
        float send = s3 ? y[i]   : y[i+2];
        z[i] = keep + __shfl_xor(send, 4);
      }
      float w0;
      { float keep = s4 ? z[1] : z[0];
        float send = s4 ? z[0] : z[1];
        w0 = keep + __shfl_xor(send, 2);
      }
      w0 += __shfl_xor(w0, 1);
      if ((hq & 1) == 0){
        int j = s1*8 + s2*4 + s3*2 + s4;
        scr[g*16 + j] = w0;
      }
    }
    __syncthreads();

    // ---- P3: wave0 masked softmax ----
    if (t < 64){
      float v0 = scr[t];                                   // len>=64 -> always valid
      float v1 = (t+64  < len)? scr[t+64]  : -1e30f;
      float v2 = (t+128 < len)? scr[t+128] : -1e30f;
      float v3 = (t+192 < len)? scr[t+192] : -1e30f;
      float m = fmaxf(fmaxf(v0,v1), fmaxf(v2,v3));
      #pragma unroll
      for (int o=1;o<64;o<<=1) m = fmaxf(m, __shfl_xor(m,o));
      float e0 = expf(v0-m);
      float e1 = (t+64  < len)? expf(v1-m) : 0.f;
      float e2 = (t+128 < len)? expf(v2-m) : 0.f;
      float e3 = (t+192 < len)? expf(v3-m) : 0.f;
      scr[t]=e0; scr[t+64]=e1; scr[t+128]=e2; scr[t+192]=e3;
      float ss = (e0+e1)+(e2+e3);
      #pragma unroll
      for (int o=1;o<64;o<<=1) ss += __shfl_xor(ss,o);
      if (t==0) red[0] = 1.f/ss;
    }
    __syncthreads();

    // ---- P4: ctx partials (broadcast weight reads, register fragments) ----
    {
      const float4* wp = (const float4*)scr + g*4;
      float4 wa = wp[0], wb = wp[1], wc = wp[2], we = wp[3];
      float4 ca = make_float4(0.f,0.f,0.f,0.f);
      CADD(wa.x,0);  CADD(wa.y,1);  CADD(wa.z,2);  CADD(wa.w,3);
      CADD(wb.x,4);  CADD(wb.y,5);  CADD(wb.z,6);  CADD(wb.w,7);
      CADD(wc.x,8);  CADD(wc.y,9);  CADD(wc.z,10); CADD(wc.w,11);
      CADD(we.x,12); CADD(we.y,13); CADD(we.z,14); CADD(we.w,15);
      ctxP4[g*32 + ((hq + g) & 31)] = ca;
    }
    __syncthreads();

    // ---- P5: reduce partials; dec = nxt + ctx/Z; store dec_k to out row k ----
    if (t < 32){
      float4 cs = make_float4(0.f,0.f,0.f,0.f);
      #pragma unroll
      for (int g2=0; g2<16; ++g2){
        float4 p4 = ctxP4[g2*32 + ((t + g2) & 31)];
        cs.x+=p4.x; cs.y+=p4.y; cs.z+=p4.z; cs.w+=p4.w;
      }
      float inv = red[0];
      float4 nx = ((const float4*)nxtF)[t];
      float4 d = make_float4(nx.x + cs.x*inv, nx.y + cs.y*inv,
                             nx.z + cs.z*inv, nx.w + cs.w*inv);
      ((float4*)decF)[t] = d;
      if (k > 0) *((float4*)(out + ((size_t)b*S_ + k)*V_) + t) = d;
    }
    __syncthreads();
  }
}

// ---------------- pass 2: in-place logits + log-softmax over out rows 1..255 ----------------
__global__ __launch_bounds__(256) void k_logits(const float* __restrict__ Wo,
                                                const float* __restrict__ bo,
                                                float* __restrict__ out)
{
  const int b = blockIdx.x, t = threadIdx.x;
  const int v = t >> 1, half = t & 1;
  const int wid = t >> 6, lane = t & 63;
  __shared__ float xch[8];
  float4 wo4[16];
  #pragma unroll
  for (int r=0;r<16;++r) wo4[r] = ((const float4*)Wo)[v*32 + half*16 + r];
  const float bov = bo[v];

  for (int k = 1 + blockIdx.y; k < S_; k += 4){
    float* rowp = out + ((size_t)b*S_ + k)*V_;
    const float4* dr = (const float4*)rowp + half*16;
    float acc = 0.f;
    #pragma unroll
    for (int r=0;r<16;++r){
      float4 d = dr[r];
      acc = fmaf(wo4[r].x,d.x,acc); acc = fmaf(wo4[r].y,d.y,acc);
      acc = fmaf(wo4[r].z,d.z,acc); acc = fmaf(wo4[r].w,d.w,acc);
    }
    acc += __shfl_xor(acc, 1);          // both half-threads now hold the full dot
    float logit = acc + bov;
    float m = logit;
    #pragma unroll
    for (int o=1;o<64;o<<=1) m = fmaxf(m, __shfl_xor(m,o));
    if (lane==0) xch[wid] = m;
    __syncthreads();
    float M = fmaxf(fmaxf(xch[0],xch[1]), fmaxf(xch[2],xch[3]));
    float e = (half==0) ? expf(logit - M) : 0.f;   // count each v once
    float s = e;
    #pragma unroll
    for (int o=1;o<64;o<<=1) s += __shfl_xor(s,o);
    if (lane==0) xch[4+wid] = s;
    __syncthreads();
    float Ss = (xch[4]+xch[5]) + (xch[6]+xch[7]);
    if (half==0) rowp[v] = logit - M - logf(Ss);
    // no trailing barrier needed: next iter's xch[0..3] writes are disjoint from
    // this iter's xch[4..7] reads, and the next first barrier orders the rest.
  }
}

extern "C" void kernel_launch(void* const* d_in, const int* in_sizes, int n_in,
                              void* d_out, int out_size, void* d_ws, size_t ws_size,
                              hipStream_t stream)
{
  const void* ohin   = d_in[0];
  const void* ohout  = d_in[1];
  const void* maskp  = d_in[2];
  const void* W_emb  = d_in[3];
  const void* b_emb  = d_in[4];
  const void* W_ih_e = d_in[5];
  const void* W_hh_e = d_in[6];
  const void* b_ih_e = d_in[7];
  const void* b_hh_e = d_in[8];
  const void* W_e2d  = d_in[9];
  const void* b_e2d  = d_in[10];
  const void* W_ih_d = d_in[11];
  const void* W_hh_d = d_in[12];
  const void* b_ih_d = d_in[13];
  const void* b_hh_d = d_in[14];
  const void* W_out  = d_in[15];
  const void* b_out  = d_in[16];
  float* out = (float*)d_out;

  char* ws = (char*)d_ws;
  int* idsIn   = (int*)ws;   ws += (size_t)B_*S_*sizeof(int);
  int* idsOut  = (int*)ws;   ws += (size_t)B_*S_*sizeof(int);
  int* lens    = (int*)ws;   ws += 2048;
  int* flag    = (int*)ws;   ws += 1024;
  float* encT  = (float*)ws; ws += (size_t)V_*H_*sizeof(float);
  float* decT  = (float*)ws; ws += (size_t)V_*H_*sizeof(float);
  float* posT  = (float*)ws; ws += (size_t)V_*H_*sizeof(float);
  float* WheF  = (float*)ws; ws += (size_t)H_*H_*sizeof(float);
  float* WddF  = (float*)ws; ws += (size_t)H_*H_*sizeof(float);
  float* WooF  = (float*)ws; ws += (size_t)H_*H_*sizeof(float);
  float* WedF  = (float*)ws; ws += (size_t)H_*H_*sizeof(float);
  float* be2dF = (float*)ws; ws += 512;
  float* boutF = (float*)ws; ws += 512;

  k_sniff<<<1, 64, 0, stream>>>((const unsigned short*)ohin, flag);
  k_lens<<<2, 256, 0, stream>>>(maskp, lens);
  k_ids<<<(B_*S_)/256, 256, 0, stream>>>(ohin, ohout, flag, idsIn, idsOut);
  k_tables<<<V_, H_, 0, stream>>>(W_emb, b_emb, W_ih_e, b_ih_e, b_hh_e,
                                  W_ih_d, b_ih_d, b_hh_d, flag, encT, decT, posT);
  k_cvt<<<(H_*H_+255)/256, 256, 0, stream>>>(W_hh_e, WheF, H_*H_, flag);
  k_cvt<<<(H_*H_+255)/256, 256, 0, stream>>>(W_hh_d, WddF, H_*H_, flag);
  k_cvt<<<(H_*H_+255)/256, 256, 0, stream>>>(W_out,  WooF, H_*H_, flag);
  k_cvt<<<(H_*H_+255)/256, 256, 0, stream>>>(W_e2d,  WedF, H_*H_, flag);
  k_cvt<<<1, 128, 0, stream>>>(b_e2d, be2dF, H_, flag);
  k_cvt<<<1, 128, 0, stream>>>(b_out, boutF, H_, flag);

  k_main<<<B_, NT_, 0, stream>>>(idsIn, idsOut, lens, encT, decT, posT,
                                 WheF, WedF, be2dF, WddF, out);

  dim3 gl(B_, 4);
  k_logits<<<gl, 256, 0, stream>>>(WooF, boutF, out);
}

// Round 9
// 3412.961 us; speedup vs baseline: 1.0193x; 1.0193x over previous
//
#include <hip/hip_runtime.h>

#define B_ 512
#define S_ 256
#define V_ 128
#define E_ 64
#define H_ 128
#define NT_ 512

// ---------------- dtype sniff: first 512 bytes of one_hot_inputs ----------------
// f32: 512B = row 0 (one 1.0f) -> 1 nonzero u16; bf16: rows 0+1 -> 2 nonzero u16
__global__ void k_sniff(const unsigned short* oh, int* flag){
  if (threadIdx.x == 0){
    int cnt = 0;
    for (int i = 0; i < 256; ++i) cnt += (oh[i] != 0);
    *flag = (cnt == 1) ? 1 : 0;
  }
}

__device__ __forceinline__ float ldf(const void* p, long i, int isf){
  if (isf) return ((const float*)p)[i];
  unsigned v = ((const unsigned short*)p)[i];
  union{unsigned u; float f;} c; c.u = v << 16; return c.f;
}

__global__ void k_cvt(const void* src, float* dst, int n, const int* flag){
  int i = blockIdx.x*blockDim.x + threadIdx.x;
  if (i < n) dst[i] = ldf(src, i, *flag);
}

// ---------------- lens: mask dtype sniffed (u8 / i32 / bf16 / f32) ----------------
__global__ void k_lens(const void* maskp, int* lens){
  int b = blockIdx.x*blockDim.x + threadIdx.x;
  if (b >= B_) return;
  const unsigned char* mc = (const unsigned char*)maskp;
  int mode;
  if (mc[0] == 1 && mc[1] == 1) mode = 0;
  else if (mc[0] == 1)          mode = 1;
  else if (mc[0] == 0x80)       mode = 2;
  else                          mode = 3;
  int cnt = 0;
  for (int j = 0; j < S_; ++j){
    long idx = (long)b*S_ + j; int v;
    if (mode == 0)      v = (mc[idx] != 0);
    else if (mode == 1) v = (((const int*)maskp)[idx] != 0);
    else if (mode == 2) v = (((const unsigned short*)maskp)[idx] != 0);
    else                v = (((const float*)maskp)[idx] > 0.5f);
    cnt += v;
  }
  lens[b] = cnt;
}

// ---------------- one-hot -> token index (dtype-adaptive) ----------------
__global__ void k_ids(const void* ohin, const void* ohout, const int* flag,
                      int* __restrict__ idsIn, int* __restrict__ idsOut){
  int row = blockIdx.x*blockDim.x + threadIdx.x;
  if (row >= B_*S_) return;
  long base = (long)row * V_;
  int isf = *flag;
  int ia = 0, ib = 0;
  if (isf){
    const float* a = (const float*)ohin; const float* c = (const float*)ohout;
    for (int v = 0; v < V_; ++v){
      if (a[base+v] > 0.5f) ia = v;
      if (c[base+v] > 0.5f) ib = v;
    }
  } else {
    const unsigned short* a = (const unsigned short*)ohin;
    const unsigned short* c = (const unsigned short*)ohout;
    for (int v = 0; v < V_; ++v){
      if (a[base+v] >= 0x3F00u) ia = v;
      if (c[base+v] >= 0x3F00u) ib = v;
    }
  }
  idsIn[row] = ia; idsOut[row] = ib;
}

// ---------------- fold embedding + input projection + biases into [V][H] tables ----------------
__global__ void k_tables(const void* W_emb, const void* b_emb,
                         const void* W_ih_e, const void* b_ih_e, const void* b_hh_e,
                         const void* W_ih_d, const void* b_ih_d, const void* b_hh_d,
                         const int* flag,
                         float* __restrict__ encT, float* __restrict__ decT,
                         float* __restrict__ posT){
  int v = blockIdx.x, h = threadIdx.x;
  int isf = *flag;
  float ae = 0.f, ad = 0.f;
  for (int e = 0; e < E_; ++e){
    float x = ldf(W_emb, (long)e*V_ + v, isf) + ldf(b_emb, e, isf);
    ae = fmaf(ldf(W_ih_e, (long)h*(E_+V_) + e, isf), x, ae);
    ad = fmaf(ldf(W_ih_d, (long)h*E_ + e, isf), x, ad);
  }
  encT[v*H_ + h] = ae + ldf(b_ih_e, h, isf) + ldf(b_hh_e, h, isf);
  decT[v*H_ + h] = ad + ldf(b_ih_d, h, isf) + ldf(b_hh_d, h, isf);
  posT[v*H_ + h] = ldf(W_ih_e, (long)h*(E_+V_) + E_ + v, isf);
}

#define CADD(s, j) do{ ca.x=fmaf((s),cR4[j].x,ca.x); ca.y=fmaf((s),cR4[j].y,ca.y); \
                       ca.z=fmaf((s),cR4[j].z,ca.z); ca.w=fmaf((s),cR4[j].w,ca.w);}while(0)

// ---------------- main serial kernel: one workgroup per batch row, all f32 ----------------
// Stores dec_k (f32) directly into out[b][k][:] for k=1..255; k_logits transforms in place.
__global__ __launch_bounds__(NT_, 4) void k_main(
    const int* __restrict__ idsIn, const int* __restrict__ idsOut, const int* __restrict__ lens,
    const float* __restrict__ encT, const float* __restrict__ decT, const float* __restrict__ posT,
    const float* __restrict__ W_hh_e, const float* __restrict__ W_e2d, const float* __restrict__ b_e2d,
    const float* __restrict__ W_hh_d, float* __restrict__ out)
{
  __shared__ __align__(16) float hv0[H_], hv1[H_], nxtF[H_], decF[H_];
  __shared__ __align__(16) float scr[S_];
  __shared__ __align__(16) float4 ctxP4[16*32];
  __shared__ float red[4];

  const int b = blockIdx.x, t = threadIdx.x;
  const int h = t >> 2, q4 = t & 3;      // matvec: 4 threads / output row
  const int hq = t & 31, g = t >> 5;     // fragments: 32 h-quads x 16 s-groups
  const int len = lens[b];

  // out row 0: log(full(EPS).at[:,0].set(1))
  if (t < V_) out[(size_t)b*S_*V_ + t] = (t==0) ? 0.f : -46.051701859880914f;

  // encoder recurrent weights (XOR-staggered)
  float4 wq[8];
  #pragma unroll
  for (int r=0;r<8;++r) wq[r] = ((const float4*)W_hh_e)[h*32 + q4*8 + (r^q4)];

  float4 cR4[16];   // enc[s][hq*4..+3] for s = g*16+j  (single f32 copy, scores+ctx)
  #pragma unroll
  for (int j=0;j<16;++j) cR4[j] = make_float4(0.f,0.f,0.f,0.f);

  if (t < H_){ hv0[t]=0.f; hv1[t]=0.f; }
  __syncthreads();

  // -------- encoder: outer dynamic group loop, inner unrolled 16 steps --------
  // Capture is cR4[LITERAL j] under uniform predicate (g==grp) -> SROA-safe, no scratch.
  const int* idsInB = idsIn + b*S_;
  int cur = 0;
  for (int grp = 0; grp < 16; ++grp){
    #pragma unroll
    for (int j = 0; j < 16; ++j){
      const int st = grp*16 + j;
      if (st < len){                      // uniform across block
        const float* hvc = cur ? hv1 : hv0;
        float* hvn = cur ? hv0 : hv1;
        const float4* hp = (const float4*)(hvc + q4*32);
        float a0=0.f, a1=0.f;
        #pragma unroll
        for (int r=0;r<8;r+=2){
          float4 u = hp[r^q4], v = hp[(r+1)^q4];
          a0 = fmaf(wq[r].x,u.x,a0);   a0 = fmaf(wq[r].y,u.y,a0);
          a0 = fmaf(wq[r].z,u.z,a0);   a0 = fmaf(wq[r].w,u.w,a0);
          a1 = fmaf(wq[r+1].x,v.x,a1); a1 = fmaf(wq[r+1].y,v.y,a1);
          a1 = fmaf(wq[r+1].z,v.z,a1); a1 = fmaf(wq[r+1].w,v.w,a1);
        }
        float acc = a0 + a1;
        acc += __shfl_xor(acc,1); acc += __shfl_xor(acc,2);
        if (q4==0){
          float pre = acc + encT[idsInB[st]*H_ + h];
          if (st < V_) pre += posT[st*H_ + h];
          hvn[h] = tanhf(pre);
        }
        __syncthreads();
        cur ^= 1;
      }
      // capture enc row st (= state after step st; frozen state when st>=len)
      if (g == grp) cR4[j] = ((const float4*)(cur ? hv1 : hv0))[hq];
    }
  }
  const float* hvF = cur ? hv1 : hv0;

  // decoder recurrent weights overwrite wq (encoder weights dead)
  #pragma unroll
  for (int r=0;r<8;++r) wq[r] = ((const float4*)W_hh_d)[h*32 + q4*8 + (r^q4)];

  const int* idsOutB = idsOut + b*S_;

  // -------- decode loop (reference order; logits deferred to k_logits) --------
  for (int k=0; k<S_; ++k){
    // ---- P1: nxt ----
    if (k == 0){
      const float4* hp  = (const float4*)(hvF + q4*32);
      const float4* We4 = (const float4*)W_e2d + h*32 + q4*8;
      float a = 0.f;
      #pragma unroll
      for (int r=0;r<8;++r){ float4 u = hp[r]; float4 w = We4[r];
        a = fmaf(w.x,u.x,a); a = fmaf(w.y,u.y,a);
        a = fmaf(w.z,u.z,a); a = fmaf(w.w,u.w,a); }
      a += __shfl_xor(a,1); a += __shfl_xor(a,2);
      if (q4==0) nxtF[h] = a + b_e2d[h];
    } else {
      int id = idsOutB[k-1];
      const float4* dp = (const float4*)decF + q4*8;
      float a0=0.f, a1=0.f;
      #pragma unroll
      for (int r=0;r<8;r+=2){
        float4 u = dp[r^q4], v = dp[(r+1)^q4];
        a0 = fmaf(wq[r].x,u.x,a0);   a0 = fmaf(wq[r].y,u.y,a0);
        a0 = fmaf(wq[r].z,u.z,a0);   a0 = fmaf(wq[r].w,u.w,a0);
        a1 = fmaf(wq[r+1].x,v.x,a1); a1 = fmaf(wq[r+1].y,v.y,a1);
        a1 = fmaf(wq[r+1].z,v.z,a1); a1 = fmaf(wq[r+1].w,v.w,a1);
      }
      float acc = a0 + a1;
      acc += __shfl_xor(acc,1); acc += __shfl_xor(acc,2);
      if (q4==0) nxtF[h] = tanhf(acc + decT[id*H_ + h]);
    }
    __syncthreads();

    // ---- P2: scores via per-lane partials + half-wave reduce-scatter ----
    {
      float4 nx = ((const float4*)nxtF)[hq];
      float p[16];
      #pragma unroll
      for (int j=0;j<16;++j){
        float s =      cR4[j].x*nx.x;
        s = fmaf(cR4[j].y,nx.y,s); s = fmaf(cR4[j].z,nx.z,s); s = fmaf(cR4[j].w,nx.w,s);
        p[j] = s;
      }
      const int s1 = (hq>>4)&1, s2=(hq>>3)&1, s3=(hq>>2)&1, s4=(hq>>1)&1;
      float x[8];
      #pragma unroll
      for (int i=0;i<8;++i){
        float keep = s1 ? p[i+8] : p[i];
        float send = s1 ? p[i]   : p[i+8];
        x[i] = keep + __shfl_xor(send, 16);
      }
      float y[4];
      #pragma unroll
      for (int i=0;i<4;++i){
        float keep = s2 ? x[i+4] : x[i];
        float send = s2 ? x[i]   : x[i+4];
        y[i] = keep + __shfl_xor(send, 8);
      }
      float z[2];
      #pragma unroll
      for (int i=0;i<2;++i){
        float keep = s3 ? y[i+2] : y[i];
        float send = s3 ? y[i]   : y[i+2];
        z[i] = keep + __shfl_xor(send, 4);
      }
      float w0;
      { float keep = s4 ? z[1] : z[0];
        float send = s4 ? z[0] : z[1];
        w0 = keep + __shfl_xor(send, 2);
      }
      w0 += __shfl_xor(w0, 1);
      if ((hq & 1) == 0){
        int j = s1*8 + s2*4 + s3*2 + s4;
        scr[g*16 + j] = w0;
      }
    }
    __syncthreads();

    // ---- P3: wave0 masked softmax ----
    if (t < 64){
      float v0 = scr[t];                                   // len>=64 -> always valid
      float v1 = (t+64  < len)? scr[t+64]  : -1e30f;
      float v2 = (t+128 < len)? scr[t+128] : -1e30f;
      float v3 = (t+192 < len)? scr[t+192] : -1e30f;
      float m = fmaxf(fmaxf(v0,v1), fmaxf(v2,v3));
      #pragma unroll
      for (int o=1;o<64;o<<=1) m = fmaxf(m, __shfl_xor(m,o));
      float e0 = expf(v0-m);
      float e1 = (t+64  < len)? expf(v1-m) : 0.f;
      float e2 = (t+128 < len)? expf(v2-m) : 0.f;
      float e3 = (t+192 < len)? expf(v3-m) : 0.f;
      scr[t]=e0; scr[t+64]=e1; scr[t+128]=e2; scr[t+192]=e3;
      float ss = (e0+e1)+(e2+e3);
      #pragma unroll
      for (int o=1;o<64;o<<=1) ss += __shfl_xor(ss,o);
      if (t==0) red[0] = 1.f/ss;
    }
    __syncthreads();

    // ---- P4: ctx partials (broadcast weight reads, register fragments) ----
    {
      const float4* wp = (const float4*)scr + g*4;
      float4 wa = wp[0], wb = wp[1], wc = wp[2], we = wp[3];
      float4 ca = make_float4(0.f,0.f,0.f,0.f);
      CADD(wa.x,0);  CADD(wa.y,1);  CADD(wa.z,2);  CADD(wa.w,3);
      CADD(wb.x,4);  CADD(wb.y,5);  CADD(wb.z,6);  CADD(wb.w,7);
      CADD(wc.x,8);  CADD(wc.y,9);  CADD(wc.z,10); CADD(wc.w,11);
      CADD(we.x,12); CADD(we.y,13); CADD(we.z,14); CADD(we.w,15);
      ctxP4[g*32 + ((hq + g) & 31)] = ca;
    }
    __syncthreads();

    // ---- P5: reduce partials; dec = nxt + ctx/Z; store dec_k to out row k ----
    if (t < 32){
      float4 cs = make_float4(0.f,0.f,0.f,0.f);
      #pragma unroll
      for (int g2=0; g2<16; ++g2){
        float4 p4 = ctxP4[g2*32 + ((t + g2) & 31)];
        cs.x+=p4.x; cs.y+=p4.y; cs.z+=p4.z; cs.w+=p4.w;
      }
      float inv = red[0];
      float4 nx = ((const float4*)nxtF)[t];
      float4 d = make_float4(nx.x + cs.x*inv, nx.y + cs.y*inv,
                             nx.z + cs.z*inv, nx.w + cs.w*inv);
      ((float4*)decF)[t] = d;
      if (k > 0) *((float4*)(out + ((size_t)b*S_ + k)*V_) + t) = d;
    }
    __syncthreads();
  }
}

// ---------------- pass 2: in-place logits + log-softmax over out rows 1..255 ----------------
__global__ __launch_bounds__(256) void k_logits(const float* __restrict__ Wo,
                                                const float* __restrict__ bo,
                                                float* __restrict__ out)
{
  const int b = blockIdx.x, t = threadIdx.x;
  const int v = t >> 1, half = t & 1;
  const int wid = t >> 6, lane = t & 63;
  __shared__ float xch[8];
  float4 wo4[16];
  #pragma unroll
  for (int r=0;r<16;++r) wo4[r] = ((const float4*)Wo)[v*32 + half*16 + r];
  const float bov = bo[v];

  for (int k = 1 + blockIdx.y; k < S_; k += 8){
    float* rowp = out + ((size_t)b*S_ + k)*V_;
    const float4* dr = (const float4*)rowp + half*16;
    float acc = 0.f;
    #pragma unroll
    for (int r=0;r<16;++r){
      float4 d = dr[r];
      acc = fmaf(wo4[r].x,d.x,acc); acc = fmaf(wo4[r].y,d.y,acc);
      acc = fmaf(wo4[r].z,d.z,acc); acc = fmaf(wo4[r].w,d.w,acc);
    }
    acc += __shfl_xor(acc, 1);          // both half-threads now hold the full dot
    float logit = acc + bov;
    float m = logit;
    #pragma unroll
    for (int o=1;o<64;o<<=1) m = fmaxf(m, __shfl_xor(m,o));
    if (lane==0) xch[wid] = m;
    __syncthreads();
    float M = fmaxf(fmaxf(xch[0],xch[1]), fmaxf(xch[2],xch[3]));
    float e = (half==0) ? expf(logit - M) : 0.f;   // count each v once
    float s = e;
    #pragma unroll
    for (int o=1;o<64;o<<=1) s += __shfl_xor(s,o);
    if (lane==0) xch[4+wid] = s;
    __syncthreads();
    float Ss = (xch[4]+xch[5]) + (xch[6]+xch[7]);
    if (half==0) rowp[v] = logit - M - logf(Ss);
    __syncthreads();   // protect xch[0..3] of next iteration
  }
}

extern "C" void kernel_launch(void* const* d_in, const int* in_sizes, int n_in,
                              void* d_out, int out_size, void* d_ws, size_t ws_size,
                              hipStream_t stream)
{
  const void* ohin   = d_in[0];
  const void* ohout  = d_in[1];
  const void* maskp  = d_in[2];
  const void* W_emb  = d_in[3];
  const void* b_emb  = d_in[4];
  const void* W_ih_e = d_in[5];
  const void* W_hh_e = d_in[6];
  const void* b_ih_e = d_in[7];
  const void* b_hh_e = d_in[8];
  const void* W_e2d  = d_in[9];
  const void* b_e2d  = d_in[10];
  const void* W_ih_d = d_in[11];
  const void* W_hh_d = d_in[12];
  const void* b_ih_d = d_in[13];
  const void* b_hh_d = d_in[14];
  const void* W_out  = d_in[15];
  const void* b_out  = d_in[16];
  float* out = (float*)d_out;

  char* ws = (char*)d_ws;
  int* idsIn   = (int*)ws;   ws += (size_t)B_*S_*sizeof(int);
  int* idsOut  = (int*)ws;   ws += (size_t)B_*S_*sizeof(int);
  int* lens    = (int*)ws;   ws += 2048;
  int* flag    = (int*)ws;   ws += 1024;
  float* encT  = (float*)ws; ws += (size_t)V_*H_*sizeof(float);
  float* decT  = (float*)ws; ws += (size_t)V_*H_*sizeof(float);
  float* posT  = (float*)ws; ws += (size_t)V_*H_*sizeof(float);
  float* WheF  = (float*)ws; ws += (size_t)H_*H_*sizeof(float);
  float* WddF  = (float*)ws; ws += (size_t)H_*H_*sizeof(float);
  float* WooF  = (float*)ws; ws += (size_t)H_*H_*sizeof(float);
  float* WedF  = (float*)ws; ws += (size_t)H_*H_*sizeof(float);
  float* be2dF = (float*)ws; ws += 512;
  float* boutF = (float*)ws; ws += 512;

  k_sniff<<<1, 64, 0, stream>>>((const unsigned short*)ohin, flag);
  k_lens<<<2, 256, 0, stream>>>(maskp, lens);
  k_ids<<<(B_*S_)/256, 256, 0, stream>>>(ohin, ohout, flag, idsIn, idsOut);
  k_tables<<<V_, H_, 0, stream>>>(W_emb, b_emb, W_ih_e, b_ih_e, b_hh_e,
                                  W_ih_d, b_ih_d, b_hh_d, flag, encT, decT, posT);
  k_cvt<<<(H_*H_+255)/256, 256, 0, stream>>>(W_hh_e, WheF, H_*H_, flag);
  k_cvt<<<(H_*H_+255)/256, 256, 0, stream>>>(W_hh_d, WddF, H_*H_, flag);
  k_cvt<<<(H_*H_+255)/256, 256, 0, stream>>>(W_out,  WooF, H_*H_, flag);
  k_cvt<<<(H_*H_+255)/256, 256, 0, stream>>>(W_e2d,  WedF, H_*H_, flag);
  k_cvt<<<1, 128, 0, stream>>>(b_e2d, be2dF, H_, flag);
  k_cvt<<<1, 128, 0, stream>>>(b_out, boutF, H_, flag);

  k_main<<<B_, NT_, 0, stream>>>(idsIn, idsOut, lens, encT, decT, posT,
                                 WheF, WedF, be2dF, WddF, out);

  dim3 gl(B_, 8);
  k_logits<<<gl, 256, 0, stream>>>(WooF, boutF, out);
}

// Round 10
// 3342.196 us; speedup vs baseline: 1.0409x; 1.0212x over previous
//
#include <hip/hip_runtime.h>

#define B_ 512
#define S_ 256
#define V_ 128
#define E_ 64
#define H_ 128
#define NT_ 512

// ---------------- dtype sniff: first 512 bytes of one_hot_inputs ----------------
// f32: 512B = row 0 (one 1.0f) -> 1 nonzero u16; bf16: rows 0+1 -> 2 nonzero u16
__global__ void k_sniff(const unsigned short* oh, int* flag){
  if (threadIdx.x == 0){
    int cnt = 0;
    for (int i = 0; i < 256; ++i) cnt += (oh[i] != 0);
    *flag = (cnt == 1) ? 1 : 0;
  }
}

__device__ __forceinline__ float ldf(const void* p, long i, int isf){
  if (isf) return ((const float*)p)[i];
  unsigned v = ((const unsigned short*)p)[i];
  union{unsigned u; float f;} c; c.u = v << 16; return c.f;
}

__global__ void k_cvt(const void* src, float* dst, int n, const int* flag){
  int i = blockIdx.x*blockDim.x + threadIdx.x;
  if (i < n) dst[i] = ldf(src, i, *flag);
}

// ---------------- lens: mask dtype sniffed (u8 / i32 / bf16 / f32) ----------------
__global__ void k_lens(const void* maskp, int* lens){
  int b = blockIdx.x*blockDim.x + threadIdx.x;
  if (b >= B_) return;
  const unsigned char* mc = (const unsigned char*)maskp;
  int mode;
  if (mc[0] == 1 && mc[1] == 1) mode = 0;
  else if (mc[0] == 1)          mode = 1;
  else if (mc[0] == 0x80)       mode = 2;
  else                          mode = 3;
  int cnt = 0;
  for (int j = 0; j < S_; ++j){
    long idx = (long)b*S_ + j; int v;
    if (mode == 0)      v = (mc[idx] != 0);
    else if (mode == 1) v = (((const int*)maskp)[idx] != 0);
    else if (mode == 2) v = (((const unsigned short*)maskp)[idx] != 0);
    else                v = (((const float*)maskp)[idx] > 0.5f);
    cnt += v;
  }
  lens[b] = cnt;
}

// ---------------- one-hot -> token index (dtype-adaptive) ----------------
__global__ void k_ids(const void* ohin, const void* ohout, const int* flag,
                      int* __restrict__ idsIn, int* __restrict__ idsOut){
  int row = blockIdx.x*blockDim.x + threadIdx.x;
  if (row >= B_*S_) return;
  long base = (long)row * V_;
  int isf = *flag;
  int ia = 0, ib = 0;
  if (isf){
    const float* a = (const float*)ohin; const float* c = (const float*)ohout;
    for (int v = 0; v < V_; ++v){
      if (a[base+v] > 0.5f) ia = v;
      if (c[base+v] > 0.5f) ib = v;
    }
  } else {
    const unsigned short* a = (const unsigned short*)ohin;
    const unsigned short* c = (const unsigned short*)ohout;
    for (int v = 0; v < V_; ++v){
      if (a[base+v] >= 0x3F00u) ia = v;
      if (c[base+v] >= 0x3F00u) ib = v;
    }
  }
  idsIn[row] = ia; idsOut[row] = ib;
}

// ---------------- fold embedding + input projection + biases into [V][H] tables ----------------
__global__ void k_tables(const void* W_emb, const void* b_emb,
                         const void* W_ih_e, const void* b_ih_e, const void* b_hh_e,
                         const void* W_ih_d, const void* b_ih_d, const void* b_hh_d,
                         const int* flag,
                         float* __restrict__ encT, float* __restrict__ decT,
                         float* __restrict__ posT){
  int v = blockIdx.x, h = threadIdx.x;
  int isf = *flag;
  float ae = 0.f, ad = 0.f;
  for (int e = 0; e < E_; ++e){
    float x = ldf(W_emb, (long)e*V_ + v, isf) + ldf(b_emb, e, isf);
    ae = fmaf(ldf(W_ih_e, (long)h*(E_+V_) + e, isf), x, ae);
    ad = fmaf(ldf(W_ih_d, (long)h*E_ + e, isf), x, ad);
  }
  encT[v*H_ + h] = ae + ldf(b_ih_e, h, isf) + ldf(b_hh_e, h, isf);
  decT[v*H_ + h] = ad + ldf(b_ih_d, h, isf) + ldf(b_hh_d, h, isf);
  posT[v*H_ + h] = ldf(W_ih_e, (long)h*(E_+V_) + E_ + v, isf);
}

#define FRAG_LIST(F) F(0) F(1) F(2) F(3) F(4) F(5) F(6) F(7) \
                     F(8) F(9) F(10) F(11) F(12) F(13) F(14) F(15)

// 128-dot with XOR-staggered reads; W literal-indexed (wq[0..7]), hp[LIT^q4]
#define MV8(ACC0, ACC1, BP) \
  { float4 u,v; \
    u = (BP)[0^q4]; v = (BP)[1^q4]; \
    ACC0 = fmaf(wq[0].x,u.x,ACC0); ACC0 = fmaf(wq[0].y,u.y,ACC0); \
    ACC0 = fmaf(wq[0].z,u.z,ACC0); ACC0 = fmaf(wq[0].w,u.w,ACC0); \
    ACC1 = fmaf(wq[1].x,v.x,ACC1); ACC1 = fmaf(wq[1].y,v.y,ACC1); \
    ACC1 = fmaf(wq[1].z,v.z,ACC1); ACC1 = fmaf(wq[1].w,v.w,ACC1); \
    u = (BP)[2^q4]; v = (BP)[3^q4]; \
    ACC0 = fmaf(wq[2].x,u.x,ACC0); ACC0 = fmaf(wq[2].y,u.y,ACC0); \
    ACC0 = fmaf(wq[2].z,u.z,ACC0); ACC0 = fmaf(wq[2].w,u.w,ACC0); \
    ACC1 = fmaf(wq[3].x,v.x,ACC1); ACC1 = fmaf(wq[3].y,v.y,ACC1); \
    ACC1 = fmaf(wq[3].z,v.z,ACC1); ACC1 = fmaf(wq[3].w,v.w,ACC1); \
    u = (BP)[4^q4]; v = (BP)[5^q4]; \
    ACC0 = fmaf(wq[4].x,u.x,ACC0); ACC0 = fmaf(wq[4].y,u.y,ACC0); \
    ACC0 = fmaf(wq[4].z,u.z,ACC0); ACC0 = fmaf(wq[4].w,u.w,ACC0); \
    ACC1 = fmaf(wq[5].x,v.x,ACC1); ACC1 = fmaf(wq[5].y,v.y,ACC1); \
    ACC1 = fmaf(wq[5].z,v.z,ACC1); ACC1 = fmaf(wq[5].w,v.w,ACC1); \
    u = (BP)[6^q4]; v = (BP)[7^q4]; \
    ACC0 = fmaf(wq[6].x,u.x,ACC0); ACC0 = fmaf(wq[6].y,u.y,ACC0); \
    ACC0 = fmaf(wq[6].z,u.z,ACC0); ACC0 = fmaf(wq[6].w,u.w,ACC0); \
    ACC1 = fmaf(wq[7].x,v.x,ACC1); ACC1 = fmaf(wq[7].y,v.y,ACC1); \
    ACC1 = fmaf(wq[7].z,v.z,ACC1); ACC1 = fmaf(wq[7].w,v.w,ACC1); }

// ---------------- main serial kernel: one workgroup per batch row, all f32 ----------------
// Enc fragments live in 16 NAMED float4 registers (no aggregate -> no scratch).
// Stores dec_k (f32) into out[b][k][:] for k=1..255; k_logits transforms in place.
__global__ __launch_bounds__(NT_, 4) void k_main(
    const int* __restrict__ idsIn, const int* __restrict__ idsOut, const int* __restrict__ lens,
    const float* __restrict__ encT, const float* __restrict__ decT, const float* __restrict__ posT,
    const float* __restrict__ W_hh_e, const float* __restrict__ W_e2d, const float* __restrict__ b_e2d,
    const float* __restrict__ W_hh_d, float* __restrict__ out)
{
  __shared__ __align__(16) float hv0[H_], hv1[H_], nxtF[H_], decF[H_];
  __shared__ __align__(16) float scr[S_];
  __shared__ __align__(16) float4 ctxP4[16*32];
  __shared__ float red[4];

  const int b = blockIdx.x, t = threadIdx.x;
  const int h = t >> 2, q4 = t & 3;      // matvec: 4 threads / output row
  const int hq = t & 31, g = t >> 5;     // fragments: 32 h-quads x 16 s-groups
  const int len = lens[b];

  // out row 0: log(full(EPS).at[:,0].set(1))
  if (t < V_) out[(size_t)b*S_*V_ + t] = (t==0) ? 0.f : -46.051701859880914f;

  // encoder recurrent weights (XOR-staggered, literal-indexed everywhere)
  float4 wq[8];
  #pragma unroll
  for (int r=0;r<8;++r) wq[r] = ((const float4*)W_hh_e)[h*32 + q4*8 + (r^q4)];

  // NAMED enc fragments: cJ = enc[g*16+J][hq*4..hq*4+3]
  #define DECL_C(J) float4 c##J = make_float4(0.f,0.f,0.f,0.f);
  FRAG_LIST(DECL_C)
  #undef DECL_C

  if (t < H_){ hv0[t]=0.f; hv1[t]=0.f; }
  __syncthreads();

  // -------- encoder: dynamic grp loop x 16 macro-expanded steps; named captures --------
  const int* idsInB = idsIn + b*S_;
  int cur = 0;
  for (int grp = 0; grp < 16; ++grp){
    #define ENCSTEP(J) { \
      const int st = grp*16 + (J); \
      if (st < len){ \
        const float* hvc = cur ? hv1 : hv0; \
        float* hvn = cur ? hv0 : hv1; \
        const float4* hp = (const float4*)(hvc + q4*32); \
        float a0=0.f, a1=0.f; \
        MV8(a0, a1, hp) \
        float acc = a0 + a1; \
        acc += __shfl_xor(acc,1); acc += __shfl_xor(acc,2); \
        if (q4==0){ \
          float pre = acc + encT[idsInB[st]*H_ + h]; \
          if (st < V_) pre += posT[st*H_ + h]; \
          hvn[h] = tanhf(pre); \
        } \
        __syncthreads(); \
        cur ^= 1; \
      } \
      if (g == grp) c##J = ((const float4*)(cur ? hv1 : hv0))[hq]; \
    }
    FRAG_LIST(ENCSTEP)
    #undef ENCSTEP
  }
  const float* hvF = cur ? hv1 : hv0;

  // decoder recurrent weights overwrite wq (encoder weights dead)
  #pragma unroll
  for (int r=0;r<8;++r) wq[r] = ((const float4*)W_hh_d)[h*32 + q4*8 + (r^q4)];

  const int* idsOutB = idsOut + b*S_;

  // -------- decode loop (reference order; logits deferred to k_logits) --------
  for (int k=0; k<S_; ++k){
    // ---- P1: nxt ----
    if (k == 0){
      const float4* hp  = (const float4*)(hvF + q4*32);
      const float4* We4 = (const float4*)W_e2d + h*32 + q4*8;
      float a = 0.f;
      #pragma unroll
      for (int r=0;r<8;++r){ float4 u = hp[r]; float4 w = We4[r];
        a = fmaf(w.x,u.x,a); a = fmaf(w.y,u.y,a);
        a = fmaf(w.z,u.z,a); a = fmaf(w.w,u.w,a); }
      a += __shfl_xor(a,1); a += __shfl_xor(a,2);
      if (q4==0) nxtF[h] = a + b_e2d[h];
    } else {
      int id = idsOutB[k-1];
      const float4* dp = (const float4*)decF + q4*8;
      float a0=0.f, a1=0.f;
      MV8(a0, a1, dp)
      float acc = a0 + a1;
      acc += __shfl_xor(acc,1); acc += __shfl_xor(acc,2);
      if (q4==0) nxtF[h] = tanhf(acc + decT[id*H_ + h]);
    }
    __syncthreads();

    // ---- P2: scores, fully scalarized partials + half-wave reduce-scatter ----
    {
      float4 nx = ((const float4*)nxtF)[hq];
      #define DOTP(J) float p##J = fmaf(c##J.w,nx.w, fmaf(c##J.z,nx.z, \
                        fmaf(c##J.y,nx.y, c##J.x*nx.x)));
      FRAG_LIST(DOTP)
      #undef DOTP
      const int s1 = (hq>>4)&1, s2=(hq>>3)&1, s3=(hq>>2)&1, s4=(hq>>1)&1;
      float x0 = (s1? p8  : p0) + __shfl_xor(s1? p0 : p8 , 16);
      float x1 = (s1? p9  : p1) + __shfl_xor(s1? p1 : p9 , 16);
      float x2 = (s1? p10 : p2) + __shfl_xor(s1? p2 : p10, 16);
      float x3 = (s1? p11 : p3) + __shfl_xor(s1? p3 : p11, 16);
      float x4 = (s1? p12 : p4) + __shfl_xor(s1? p4 : p12, 16);
      float x5 = (s1? p13 : p5) + __shfl_xor(s1? p5 : p13, 16);
      float x6 = (s1? p14 : p6) + __shfl_xor(s1? p6 : p14, 16);
      float x7 = (s1? p15 : p7) + __shfl_xor(s1? p7 : p15, 16);
      float y0 = (s2? x4 : x0) + __shfl_xor(s2? x0 : x4, 8);
      float y1 = (s2? x5 : x1) + __shfl_xor(s2? x1 : x5, 8);
      float y2 = (s2? x6 : x2) + __shfl_xor(s2? x2 : x6, 8);
      float y3 = (s2? x7 : x3) + __shfl_xor(s2? x3 : x7, 8);
      float z0 = (s3? y2 : y0) + __shfl_xor(s3? y0 : y2, 4);
      float z1 = (s3? y3 : y1) + __shfl_xor(s3? y1 : y3, 4);
      float w0 = (s4? z1 : z0) + __shfl_xor(s4? z0 : z1, 2);
      w0 += __shfl_xor(w0, 1);
      if ((hq & 1) == 0){
        int j = s1*8 + s2*4 + s3*2 + s4;
        scr[g*16 + j] = w0;
      }
    }
    __syncthreads();

    // ---- P3: wave0 masked softmax ----
    if (t < 64){
      float v0 = scr[t];                                   // len>=64 -> always valid
      float v1 = (t+64  < len)? scr[t+64]  : -1e30f;
      float v2 = (t+128 < len)? scr[t+128] : -1e30f;
      float v3 = (t+192 < len)? scr[t+192] : -1e30f;
      float m = fmaxf(fmaxf(v0,v1), fmaxf(v2,v3));
      #pragma unroll
      for (int o=1;o<64;o<<=1) m = fmaxf(m, __shfl_xor(m,o));
      float e0 = expf(v0-m);
      float e1 = (t+64  < len)? expf(v1-m) : 0.f;
      float e2 = (t+128 < len)? expf(v2-m) : 0.f;
      float e3 = (t+192 < len)? expf(v3-m) : 0.f;
      scr[t]=e0; scr[t+64]=e1; scr[t+128]=e2; scr[t+192]=e3;
      float ss = (e0+e1)+(e2+e3);
      #pragma unroll
      for (int o=1;o<64;o<<=1) ss += __shfl_xor(ss,o);
      if (t==0) red[0] = 1.f/ss;
    }
    __syncthreads();

    // ---- P4: ctx partials (broadcast weight reads, named register fragments) ----
    {
      const float4* wp = (const float4*)scr + g*4;
      float4 wa = wp[0], wb = wp[1], wc = wp[2], we = wp[3];
      float4 ca = make_float4(0.f,0.f,0.f,0.f);
      #define CADD2(S, C) { ca.x=fmaf((S),C.x,ca.x); ca.y=fmaf((S),C.y,ca.y); \
                            ca.z=fmaf((S),C.z,ca.z); ca.w=fmaf((S),C.w,ca.w); }
      CADD2(wa.x,c0)  CADD2(wa.y,c1)  CADD2(wa.z,c2)  CADD2(wa.w,c3)
      CADD2(wb.x,c4)  CADD2(wb.y,c5)  CADD2(wb.z,c6)  CADD2(wb.w,c7)
      CADD2(wc.x,c8)  CADD2(wc.y,c9)  CADD2(wc.z,c10) CADD2(wc.w,c11)
      CADD2(we.x,c12) CADD2(we.y,c13) CADD2(we.z,c14) CADD2(we.w,c15)
      #undef CADD2
      ctxP4[g*32 + ((hq + g) & 31)] = ca;
    }
    __syncthreads();

    // ---- P5: reduce partials; dec = nxt + ctx/Z; store dec_k to out row k ----
    if (t < 32){
      float4 cs = make_float4(0.f,0.f,0.f,0.f);
      #pragma unroll
      for (int g2=0; g2<16; ++g2){
        float4 p4 = ctxP4[g2*32 + ((t + g2) & 31)];
        cs.x+=p4.x; cs.y+=p4.y; cs.z+=p4.z; cs.w+=p4.w;
      }
      float inv = red[0];
      float4 nx = ((const float4*)nxtF)[t];
      float4 d = make_float4(nx.x + cs.x*inv, nx.y + cs.y*inv,
                             nx.z + cs.z*inv, nx.w + cs.w*inv);
      ((float4*)decF)[t] = d;
      if (k > 0) *((float4*)(out + ((size_t)b*S_ + k)*V_) + t) = d;
    }
    __syncthreads();
  }
}

// ---------------- pass 2: in-place logits + log-softmax over out rows 1..255 ----------------
__global__ __launch_bounds__(256) void k_logits(const float* __restrict__ Wo,
                                                const float* __restrict__ bo,
                                                float* __restrict__ out)
{
  const int b = blockIdx.x, t = threadIdx.x;
  const int v = t >> 1, half = t & 1;
  const int wid = t >> 6, lane = t & 63;
  __shared__ float xch[8];
  float4 wo4[16];
  #pragma unroll
  for (int r=0;r<16;++r) wo4[r] = ((const float4*)Wo)[v*32 + half*16 + r];
  const float bov = bo[v];

  for (int k = 1 + blockIdx.y; k < S_; k += 8){
    float* rowp = out + ((size_t)b*S_ + k)*V_;
    const float4* dr = (const float4*)rowp + half*16;
    float acc = 0.f;
    #pragma unroll
    for (int r=0;r<16;++r){
      float4 d = dr[r];
      acc = fmaf(wo4[r].x,d.x,acc); acc = fmaf(wo4[r].y,d.y,acc);
      acc = fmaf(wo4[r].z,d.z,acc); acc = fmaf(wo4[r].w,d.w,acc);
    }
    acc += __shfl_xor(acc, 1);          // both half-threads now hold the full dot
    float logit = acc + bov;
    float m = logit;
    #pragma unroll
    for (int o=1;o<64;o<<=1) m = fmaxf(m, __shfl_xor(m,o));
    if (lane==0) xch[wid] = m;
    __syncthreads();
    float M = fmaxf(fmaxf(xch[0],xch[1]), fmaxf(xch[2],xch[3]));
    float e = (half==0) ? expf(logit - M) : 0.f;   // count each v once
    float s = e;
    #pragma unroll
    for (int o=1;o<64;o<<=1) s += __shfl_xor(s,o);
    if (lane==0) xch[4+wid] = s;
    __syncthreads();
    float Ss = (xch[4]+xch[5]) + (xch[6]+xch[7]);
    if (half==0) rowp[v] = logit - M - logf(Ss);
    __syncthreads();   // protect xch[0..3] of next iteration
  }
}

extern "C" void kernel_launch(void* const* d_in, const int* in_sizes, int n_in,
                              void* d_out, int out_size, void* d_ws, size_t ws_size,
                              hipStream_t stream)
{
  const void* ohin   = d_in[0];
  const void* ohout  = d_in[1];
  const void* maskp  = d_in[2];
  const void* W_emb  = d_in[3];
  const void* b_emb  = d_in[4];
  const void* W_ih_e = d_in[5];
  const void* W_hh_e = d_in[6];
  const void* b_ih_e = d_in[7];
  const void* b_hh_e = d_in[8];
  const void* W_e2d  = d_in[9];
  const void* b_e2d  = d_in[10];
  const void* W_ih_d = d_in[11];
  const void* W_hh_d = d_in[12];
  const void* b_ih_d = d_in[13];
  const void* b_hh_d = d_in[14];
  const void* W_out  = d_in[15];
  const void* b_out  = d_in[16];
  float* out = (float*)d_out;

  char* ws = (char*)d_ws;
  int* idsIn   = (int*)ws;   ws += (size_t)B_*S_*sizeof(int);
  int* idsOut  = (int*)ws;   ws += (size_t)B_*S_*sizeof(int);
  int* lens    = (int*)ws;   ws += 2048;
  int* flag    = (int*)ws;   ws += 1024;
  float* encT  = (float*)ws; ws += (size_t)V_*H_*sizeof(float);
  float* decT  = (float*)ws; ws += (size_t)V_*H_*sizeof(float);
  float* posT  = (float*)ws; ws += (size_t)V_*H_*sizeof(float);
  float* WheF  = (float*)ws; ws += (size_t)H_*H_*sizeof(float);
  float* WddF  = (float*)ws; ws += (size_t)H_*H_*sizeof(float);
  float* WooF  = (float*)ws; ws += (size_t)H_*H_*sizeof(float);
  float* WedF  = (float*)ws; ws += (size_t)H_*H_*sizeof(float);
  float* be2dF = (float*)ws; ws += 512;
  float* boutF = (float*)ws; ws += 512;

  k_sniff<<<1, 64, 0, stream>>>((const unsigned short*)ohin, flag);
  k_lens<<<2, 256, 0, stream>>>(maskp, lens);
  k_ids<<<(B_*S_)/256, 256, 0, stream>>>(ohin, ohout, flag, idsIn, idsOut);
  k_tables<<<V_, H_, 0, stream>>>(W_emb, b_emb, W_ih_e, b_ih_e, b_hh_e,
                                  W_ih_d, b_ih_d, b_hh_d, flag, encT, decT, posT);
  k_cvt<<<(H_*H_+255)/256, 256, 0, stream>>>(W_hh_e, WheF, H_*H_, flag);
  k_cvt<<<(H_*H_+255)/256, 256, 0, stream>>>(W_hh_d, WddF, H_*H_, flag);
  k_cvt<<<(H_*H_+255)/256, 256, 0, stream>>>(W_out,  WooF, H_*H_, flag);
  k_cvt<<<(H_*H_+255)/256, 256, 0, stream>>>(W_e2d,  WedF, H_*H_, flag);
  k_cvt<<<1, 128, 0, stream>>>(b_e2d, be2dF, H_, flag);
  k_cvt<<<1, 128, 0, stream>>>(b_out, boutF, H_, flag);

  k_main<<<B_, NT_, 0, stream>>>(idsIn, idsOut, lens, encT, decT, posT,
                                 WheF, WedF, be2dF, WddF, out);

  dim3 gl(B_, 8);
  k_logits<<<gl, 256, 0, stream>>>(WooF, boutF, out);
}

// Round 11
// 3314.760 us; speedup vs baseline: 1.0495x; 1.0083x over previous
//
#include <hip/hip_runtime.h>

#define B_ 512
#define S_ 256
#define V_ 128
#define E_ 64
#define H_ 128
#define NT_ 512

// ---------------- dtype sniff: first 512 bytes of one_hot_inputs ----------------
// f32: 512B = row 0 (one 1.0f) -> 1 nonzero u16; bf16: rows 0+1 -> 2 nonzero u16
__global__ void k_sniff(const unsigned short* oh, int* flag){
  if (threadIdx.x == 0){
    int cnt = 0;
    for (int i = 0; i < 256; ++i) cnt += (oh[i] != 0);
    *flag = (cnt == 1) ? 1 : 0;
  }
}

__device__ __forceinline__ float ldf(const void* p, long i, int isf){
  if (isf) return ((const float*)p)[i];
  unsigned v = ((const unsigned short*)p)[i];
  union{unsigned u; float f;} c; c.u = v << 16; return c.f;
}

__global__ void k_cvt(const void* src, float* dst, int n, const int* flag){
  int i = blockIdx.x*blockDim.x + threadIdx.x;
  if (i < n) dst[i] = ldf(src, i, *flag);
}

// ---------------- lens: mask dtype sniffed (u8 / i32 / bf16 / f32) ----------------
__global__ void k_lens(const void* maskp, int* lens){
  int b = blockIdx.x*blockDim.x + threadIdx.x;
  if (b >= B_) return;
  const unsigned char* mc = (const unsigned char*)maskp;
  int mode;
  if (mc[0] == 1 && mc[1] == 1) mode = 0;
  else if (mc[0] == 1)          mode = 1;
  else if (mc[0] == 0x80)       mode = 2;
  else                          mode = 3;
  int cnt = 0;
  for (int j = 0; j < S_; ++j){
    long idx = (long)b*S_ + j; int v;
    if (mode == 0)      v = (mc[idx] != 0);
    else if (mode == 1) v = (((const int*)maskp)[idx] != 0);
    else if (mode == 2) v = (((const unsigned short*)maskp)[idx] != 0);
    else                v = (((const float*)maskp)[idx] > 0.5f);
    cnt += v;
  }
  lens[b] = cnt;
}

// ---------------- one-hot -> token index (dtype-adaptive) ----------------
__global__ void k_ids(const void* ohin, const void* ohout, const int* flag,
                      int* __restrict__ idsIn, int* __restrict__ idsOut){
  int row = blockIdx.x*blockDim.x + threadIdx.x;
  if (row >= B_*S_) return;
  long base = (long)row * V_;
  int isf = *flag;
  int ia = 0, ib = 0;
  if (isf){
    const float* a = (const float*)ohin; const float* c = (const float*)ohout;
    for (int v = 0; v < V_; ++v){
      if (a[base+v] > 0.5f) ia = v;
      if (c[base+v] > 0.5f) ib = v;
    }
  } else {
    const unsigned short* a = (const unsigned short*)ohin;
    const unsigned short* c = (const unsigned short*)ohout;
    for (int v = 0; v < V_; ++v){
      if (a[base+v] >= 0x3F00u) ia = v;
      if (c[base+v] >= 0x3F00u) ib = v;
    }
  }
  idsIn[row] = ia; idsOut[row] = ib;
}

// ---------------- fold embedding + input projection + biases into [V][H] tables ----------------
__global__ void k_tables(const void* W_emb, const void* b_emb,
                         const void* W_ih_e, const void* b_ih_e, const void* b_hh_e,
                         const void* W_ih_d, const void* b_ih_d, const void* b_hh_d,
                         const int* flag,
                         float* __restrict__ encT, float* __restrict__ decT,
                         float* __restrict__ posT){
  int v = blockIdx.x, h = threadIdx.x;
  int isf = *flag;
  float ae = 0.f, ad = 0.f;
  for (int e = 0; e < E_; ++e){
    float x = ldf(W_emb, (long)e*V_ + v, isf) + ldf(b_emb, e, isf);
    ae = fmaf(ldf(W_ih_e, (long)h*(E_+V_) + e, isf), x, ae);
    ad = fmaf(ldf(W_ih_d, (long)h*E_ + e, isf), x, ad);
  }
  encT[v*H_ + h] = ae + ldf(b_ih_e, h, isf) + ldf(b_hh_e, h, isf);
  decT[v*H_ + h] = ad + ldf(b_ih_d, h, isf) + ldf(b_hh_d, h, isf);
  posT[v*H_ + h] = ldf(W_ih_e, (long)h*(E_+V_) + E_ + v, isf);
}

#define FRAG_LIST(F) F(0) F(1) F(2) F(3) F(4) F(5) F(6) F(7) \
                     F(8) F(9) F(10) F(11) F(12) F(13) F(14) F(15)

// 128-dot with XOR-staggered reads; W literal-indexed (wq[0..7]), hp[LIT^q4]
#define MV8(ACC0, ACC1, BP) \
  { float4 u,v; \
    u = (BP)[0^q4]; v = (BP)[1^q4]; \
    ACC0 = fmaf(wq[0].x,u.x,ACC0); ACC0 = fmaf(wq[0].y,u.y,ACC0); \
    ACC0 = fmaf(wq[0].z,u.z,ACC0); ACC0 = fmaf(wq[0].w,u.w,ACC0); \
    ACC1 = fmaf(wq[1].x,v.x,ACC1); ACC1 = fmaf(wq[1].y,v.y,ACC1); \
    ACC1 = fmaf(wq[1].z,v.z,ACC1); ACC1 = fmaf(wq[1].w,v.w,ACC1); \
    u = (BP)[2^q4]; v = (BP)[3^q4]; \
    ACC0 = fmaf(wq[2].x,u.x,ACC0); ACC0 = fmaf(wq[2].y,u.y,ACC0); \
    ACC0 = fmaf(wq[2].z,u.z,ACC0); ACC0 = fmaf(wq[2].w,u.w,ACC0); \
    ACC1 = fmaf(wq[3].x,v.x,ACC1); ACC1 = fmaf(wq[3].y,v.y,ACC1); \
    ACC1 = fmaf(wq[3].z,v.z,ACC1); ACC1 = fmaf(wq[3].w,v.w,ACC1); \
    u = (BP)[4^q4]; v = (BP)[5^q4]; \
    ACC0 = fmaf(wq[4].x,u.x,ACC0); ACC0 = fmaf(wq[4].y,u.y,ACC0); \
    ACC0 = fmaf(wq[4].z,u.z,ACC0); ACC0 = fmaf(wq[4].w,u.w,ACC0); \
    ACC1 = fmaf(wq[5].x,v.x,ACC1); ACC1 = fmaf(wq[5].y,v.y,ACC1); \
    ACC1 = fmaf(wq[5].z,v.z,ACC1); ACC1 = fmaf(wq[5].w,v.w,ACC1); \
    u = (BP)[6^q4]; v = (BP)[7^q4]; \
    ACC0 = fmaf(wq[6].x,u.x,ACC0); ACC0 = fmaf(wq[6].y,u.y,ACC0); \
    ACC0 = fmaf(wq[6].z,u.z,ACC0); ACC0 = fmaf(wq[6].w,u.w,ACC0); \
    ACC1 = fmaf(wq[7].x,v.x,ACC1); ACC1 = fmaf(wq[7].y,v.y,ACC1); \
    ACC1 = fmaf(wq[7].z,v.z,ACC1); ACC1 = fmaf(wq[7].w,v.w,ACC1); }

// ---------------- main serial kernel: one workgroup per batch row, all f32 ----------------
// Enc fragments live in 16 NAMED float4 registers. VGPR budget: amdgpu_waves_per_eu(4)
// -> cap 128 (the launch_bounds(512,4) form capped at 64 and spilled everything: R8-R10).
__global__ __attribute__((amdgpu_waves_per_eu(4))) __launch_bounds__(NT_) void k_main(
    const int* __restrict__ idsIn, const int* __restrict__ idsOut, const int* __restrict__ lens,
    const float* __restrict__ encT, const float* __restrict__ decT, const float* __restrict__ posT,
    const float* __restrict__ W_hh_e, const float* __restrict__ W_e2d, const float* __restrict__ b_e2d,
    const float* __restrict__ W_hh_d, float* __restrict__ out)
{
  __shared__ __align__(16) float hv0[H_], hv1[H_], nxtF[H_], decF[H_];
  __shared__ __align__(16) float scr[S_];
  __shared__ __align__(16) float4 ctxP4[16*32];
  __shared__ float red[4];

  const int b = blockIdx.x, t = threadIdx.x;
  const int h = t >> 2, q4 = t & 3;      // matvec: 4 threads / output row
  const int hq = t & 31, g = t >> 5;     // fragments: 32 h-quads x 16 s-groups
  const int len = lens[b];

  // out row 0: log(full(EPS).at[:,0].set(1))
  if (t < V_) out[(size_t)b*S_*V_ + t] = (t==0) ? 0.f : -46.051701859880914f;

  // encoder recurrent weights (XOR-staggered, literal-indexed everywhere)
  float4 wq[8];
  #pragma unroll
  for (int r=0;r<8;++r) wq[r] = ((const float4*)W_hh_e)[h*32 + q4*8 + (r^q4)];

  // NAMED enc fragments: cJ = enc[g*16+J][hq*4..hq*4+3]
  #define DECL_C(J) float4 c##J = make_float4(0.f,0.f,0.f,0.f);
  FRAG_LIST(DECL_C)
  #undef DECL_C

  if (t < H_){ hv0[t]=0.f; hv1[t]=0.f; }
  __syncthreads();

  // -------- encoder: dynamic grp loop x 16 macro-expanded steps; named captures --------
  const int* idsInB = idsIn + b*S_;
  int cur = 0;
  for (int grp = 0; grp < 16; ++grp){
    #define ENCSTEP(J) { \
      const int st = grp*16 + (J); \
      if (st < len){ \
        const float* hvc = cur ? hv1 : hv0; \
        float* hvn = cur ? hv0 : hv1; \
        const float4* hp = (const float4*)(hvc + q4*32); \
        float a0=0.f, a1=0.f; \
        MV8(a0, a1, hp) \
        float acc = a0 + a1; \
        acc += __shfl_xor(acc,1); acc += __shfl_xor(acc,2); \
        if (q4==0){ \
          float pre = acc + encT[idsInB[st]*H_ + h]; \
          if (st < V_) pre += posT[st*H_ + h]; \
          hvn[h] = tanhf(pre); \
        } \
        __syncthreads(); \
        cur ^= 1; \
      } \
      if (g == grp) c##J = ((const float4*)(cur ? hv1 : hv0))[hq]; \
    }
    FRAG_LIST(ENCSTEP)
    #undef ENCSTEP
  }
  const float* hvF = cur ? hv1 : hv0;

  // decoder recurrent weights overwrite wq (encoder weights dead)
  #pragma unroll
  for (int r=0;r<8;++r) wq[r] = ((const float4*)W_hh_d)[h*32 + q4*8 + (r^q4)];

  const int* idsOutB = idsOut + b*S_;

  // -------- decode loop (reference order; logits deferred to k_logits) --------
  for (int k=0; k<S_; ++k){
    // ---- P1: nxt ----
    if (k == 0){
      const float4* hp  = (const float4*)(hvF + q4*32);
      const float4* We4 = (const float4*)W_e2d + h*32 + q4*8;
      float a = 0.f;
      #pragma unroll
      for (int r=0;r<8;++r){ float4 u = hp[r]; float4 w = We4[r];
        a = fmaf(w.x,u.x,a); a = fmaf(w.y,u.y,a);
        a = fmaf(w.z,u.z,a); a = fmaf(w.w,u.w,a); }
      a += __shfl_xor(a,1); a += __shfl_xor(a,2);
      if (q4==0) nxtF[h] = a + b_e2d[h];
    } else {
      int id = idsOutB[k-1];
      const float4* dp = (const float4*)decF + q4*8;
      float a0=0.f, a1=0.f;
      MV8(a0, a1, dp)
      float acc = a0 + a1;
      acc += __shfl_xor(acc,1); acc += __shfl_xor(acc,2);
      if (q4==0) nxtF[h] = tanhf(acc + decT[id*H_ + h]);
    }
    __syncthreads();

    // ---- P2: scores, fully scalarized partials + half-wave reduce-scatter ----
    {
      float4 nx = ((const float4*)nxtF)[hq];
      #define DOTP(J) float p##J = fmaf(c##J.w,nx.w, fmaf(c##J.z,nx.z, \
                        fmaf(c##J.y,nx.y, c##J.x*nx.x)));
      FRAG_LIST(DOTP)
      #undef DOTP
      const int s1 = (hq>>4)&1, s2=(hq>>3)&1, s3=(hq>>2)&1, s4=(hq>>1)&1;
      float x0 = (s1? p8  : p0) + __shfl_xor(s1? p0 : p8 , 16);
      float x1 = (s1? p9  : p1) + __shfl_xor(s1? p1 : p9 , 16);
      float x2 = (s1? p10 : p2) + __shfl_xor(s1? p2 : p10, 16);
      float x3 = (s1? p11 : p3) + __shfl_xor(s1? p3 : p11, 16);
      float x4 = (s1? p12 : p4) + __shfl_xor(s1? p4 : p12, 16);
      float x5 = (s1? p13 : p5) + __shfl_xor(s1? p5 : p13, 16);
      float x6 = (s1? p14 : p6) + __shfl_xor(s1? p6 : p14, 16);
      float x7 = (s1? p15 : p7) + __shfl_xor(s1? p7 : p15, 16);
      float y0 = (s2? x4 : x0) + __shfl_xor(s2? x0 : x4, 8);
      float y1 = (s2? x5 : x1) + __shfl_xor(s2? x1 : x5, 8);
      float y2 = (s2? x6 : x2) + __shfl_xor(s2? x2 : x6, 8);
      float y3 = (s2? x7 : x3) + __shfl_xor(s2? x3 : x7, 8);
      float z0 = (s3? y2 : y0) + __shfl_xor(s3? y0 : y2, 4);
      float z1 = (s3? y3 : y1) + __shfl_xor(s3? y1 : y3, 4);
      float w0 = (s4? z1 : z0) + __shfl_xor(s4? z0 : z1, 2);
      w0 += __shfl_xor(w0, 1);
      if ((hq & 1) == 0){
        int j = s1*8 + s2*4 + s3*2 + s4;
        scr[g*16 + j] = w0;
      }
    }
    __syncthreads();

    // ---- P3: wave0 masked softmax ----
    if (t < 64){
      float v0 = scr[t];                                   // len>=64 -> always valid
      float v1 = (t+64  < len)? scr[t+64]  : -1e30f;
      float v2 = (t+128 < len)? scr[t+128] : -1e30f;
      float v3 = (t+192 < len)? scr[t+192] : -1e30f;
      float m = fmaxf(fmaxf(v0,v1), fmaxf(v2,v3));
      #pragma unroll
      for (int o=1;o<64;o<<=1) m = fmaxf(m, __shfl_xor(m,o));
      float e0 = expf(v0-m);
      float e1 = (t+64  < len)? expf(v1-m) : 0.f;
      float e2 = (t+128 < len)? expf(v2-m) : 0.f;
      float e3 = (t+192 < len)? expf(v3-m) : 0.f;
      scr[t]=e0; scr[t+64]=e1; scr[t+128]=e2; scr[t+192]=e3;
      float ss = (e0+e1)+(e2+e3);
      #pragma unroll
      for (int o=1;o<64;o<<=1) ss += __shfl_xor(ss,o);
      if (t==0) red[0] = 1.f/ss;
    }
    __syncthreads();

    // ---- P4: ctx partials (broadcast weight reads, named register fragments) ----
    {
      const float4* wp = (const float4*)scr + g*4;
      float4 wa = wp[0], wb = wp[1], wc = wp[2], we = wp[3];
      float4 ca = make_float4(0.f,0.f,0.f,0.f);
      #define CADD2(S, C) { ca.x=fmaf((S),C.x,ca.x); ca.y=fmaf((S),C.y,ca.y); \
                            ca.z=fmaf((S),C.z,ca.z); ca.w=fmaf((S),C.w,ca.w); }
      CADD2(wa.x,c0)  CADD2(wa.y,c1)  CADD2(wa.z,c2)  CADD2(wa.w,c3)
      CADD2(wb.x,c4)  CADD2(wb.y,c5)  CADD2(wb.z,c6)  CADD2(wb.w,c7)
      CADD2(wc.x,c8)  CADD2(wc.y,c9)  CADD2(wc.z,c10) CADD2(wc.w,c11)
      CADD2(we.x,c12) CADD2(we.y,c13) CADD2(we.z,c14) CADD2(we.w,c15)
      #undef CADD2
      ctxP4[g*32 + ((hq + g) & 31)] = ca;
    }
    __syncthreads();

    // ---- P5: reduce partials; dec = nxt + ctx/Z; store dec_k to out row k ----
    if (t < 32){
      float4 cs = make_float4(0.f,0.f,0.f,0.f);
      #pragma unroll
      for (int g2=0; g2<16; ++g2){
        float4 p4 = ctxP4[g2*32 + ((t + g2) & 31)];
        cs.x+=p4.x; cs.y+=p4.y; cs.z+=p4.z; cs.w+=p4.w;
      }
      float inv = red[0];
      float4 nx = ((const float4*)nxtF)[t];
      float4 d = make_float4(nx.x + cs.x*inv, nx.y + cs.y*inv,
                             nx.z + cs.z*inv, nx.w + cs.w*inv);
      ((float4*)decF)[t] = d;
      if (k > 0) *((float4*)(out + ((size_t)b*S_ + k)*V_) + t) = d;
    }
    __syncthreads();
  }
}

// ---------------- pass 2: in-place logits + log-softmax over out rows 1..255 ----------------
__global__ __launch_bounds__(256) void k_logits(const float* __restrict__ Wo,
                                                const float* __restrict__ bo,
                                                float* __restrict__ out)
{
  const int b = blockIdx.x, t = threadIdx.x;
  const int v = t >> 1, half = t & 1;
  const int wid = t >> 6, lane = t & 63;
  __shared__ float xch[8];
  float4 wo4[16];
  #pragma unroll
  for (int r=0;r<16;++r) wo4[r] = ((const float4*)Wo)[v*32 + half*16 + r];
  const float bov = bo[v];

  for (int k = 1 + blockIdx.y; k < S_; k += 8){
    float* rowp = out + ((size_t)b*S_ + k)*V_;
    const float4* dr = (const float4*)rowp + half*16;
    float acc = 0.f;
    #pragma unroll
    for (int r=0;r<16;++r){
      float4 d = dr[r];
      acc = fmaf(wo4[r].x,d.x,acc); acc = fmaf(wo4[r].y,d.y,acc);
      acc = fmaf(wo4[r].z,d.z,acc); acc = fmaf(wo4[r].w,d.w,acc);
    }
    acc += __shfl_xor(acc, 1);          // both half-threads now hold the full dot
    float logit = acc + bov;
    float m = logit;
    #pragma unroll
    for (int o=1;o<64;o<<=1) m = fmaxf(m, __shfl_xor(m,o));
    if (lane==0) xch[wid] = m;
    __syncthreads();
    float M = fmaxf(fmaxf(xch[0],xch[1]), fmaxf(xch[2],xch[3]));
    float e = (half==0) ? expf(logit - M) : 0.f;   // count each v once
    float s = e;
    #pragma unroll
    for (int o=1;o<64;o<<=1) s += __shfl_xor(s,o);
    if (lane==0) xch[4+wid] = s;
    __syncthreads();
    float Ss = (xch[4]+xch[5]) + (xch[6]+xch[7]);
    if (half==0) rowp[v] = logit - M - logf(Ss);
    __syncthreads();   // protect xch[0..3] of next iteration
  }
}

extern "C" void kernel_launch(void* const* d_in, const int* in_sizes, int n_in,
                              void* d_out, int out_size, void* d_ws, size_t ws_size,
                              hipStream_t stream)
{
  const void* ohin   = d_in[0];
  const void* ohout  = d_in[1];
  const void* maskp  = d_in[2];
  const void* W_emb  = d_in[3];
  const void* b_emb  = d_in[4];
  const void* W_ih_e = d_in[5];
  const void* W_hh_e = d_in[6];
  const void* b_ih_e = d_in[7];
  const void* b_hh_e = d_in[8];
  const void* W_e2d  = d_in[9];
  const void* b_e2d  = d_in[10];
  const void* W_ih_d = d_in[11];
  const void* W_hh_d = d_in[12];
  const void* b_ih_d = d_in[13];
  const void* b_hh_d = d_in[14];
  const void* W_out  = d_in[15];
  const void* b_out  = d_in[16];
  float* out = (float*)d_out;

  char* ws = (char*)d_ws;
  int* idsIn   = (int*)ws;   ws += (size_t)B_*S_*sizeof(int);
  int* idsOut  = (int*)ws;   ws += (size_t)B_*S_*sizeof(int);
  int* lens    = (int*)ws;   ws += 2048;
  int* flag    = (int*)ws;   ws += 1024;
  float* encT  = (float*)ws; ws += (size_t)V_*H_*sizeof(float);
  float* decT  = (float*)ws; ws += (size_t)V_*H_*sizeof(float);
  float* posT  = (float*)ws; ws += (size_t)V_*H_*sizeof(float);
  float* WheF  = (float*)ws; ws += (size_t)H_*H_*sizeof(float);
  float* WddF  = (float*)ws; ws += (size_t)H_*H_*sizeof(float);
  float* WooF  = (float*)ws; ws += (size_t)H_*H_*sizeof(float);
  float* WedF  = (float*)ws; ws += (size_t)H_*H_*sizeof(float);
  float* be2dF = (float*)ws; ws += 512;
  float* boutF = (float*)ws; ws += 512;

  k_sniff<<<1, 64, 0, stream>>>((const unsigned short*)ohin, flag);
  k_lens<<<2, 256, 0, stream>>>(maskp, lens);
  k_ids<<<(B_*S_)/256, 256, 0, stream>>>(ohin, ohout, flag, idsIn, idsOut);
  k_tables<<<V_, H_, 0, stream>>>(W_emb, b_emb, W_ih_e, b_ih_e, b_hh_e,
                                  W_ih_d, b_ih_d, b_hh_d, flag, encT, decT, posT);
  k_cvt<<<(H_*H_+255)/256, 256, 0, stream>>>(W_hh_e, WheF, H_*H_, flag);
  k_cvt<<<(H_*H_+255)/256, 256, 0, stream>>>(W_hh_d, WddF, H_*H_, flag);
  k_cvt<<<(H_*H_+255)/256, 256, 0, stream>>>(W_out,  WooF, H_*H_, flag);
  k_cvt<<<(H_*H_+255)/256, 256, 0, stream>>>(W_e2d,  WedF, H_*H_, flag);
  k_cvt<<<1, 128, 0, stream>>>(b_e2d, be2dF, H_, flag);
  k_cvt<<<1, 128, 0, stream>>>(b_out, boutF, H_, flag);

  k_main<<<B_, NT_, 0, stream>>>(idsIn, idsOut, lens, encT, decT, posT,
                                 WheF, WedF, be2dF, WddF, out);

  dim3 gl(B_, 8);
  k_logits<<<gl, 256, 0, stream>>>(WooF, boutF, out);
}

// Round 12
// 2103.029 us; speedup vs baseline: 1.6542x; 1.5762x over previous
//
#include <hip/hip_runtime.h>

#define B_ 512
#define S_ 256
#define V_ 128
#define E_ 64
#define H_ 128
#define NT_ 512

// ---------------- dtype sniff: first 512 bytes of one_hot_inputs ----------------
// f32: 512B = row 0 (one 1.0f) -> 1 nonzero u16; bf16: rows 0+1 -> 2 nonzero u16
__global__ void k_sniff(const unsigned short* oh, int* flag){
  if (threadIdx.x == 0){
    int cnt = 0;
    for (int i = 0; i < 256; ++i) cnt += (oh[i] != 0);
    *flag = (cnt == 1) ? 1 : 0;
  }
}

__device__ __forceinline__ float ldf(const void* p, long i, int isf){
  if (isf) return ((const float*)p)[i];
  unsigned v = ((const unsigned short*)p)[i];
  union{unsigned u; float f;} c; c.u = v << 16; return c.f;
}

__global__ void k_cvt(const void* src, float* dst, int n, const int* flag){
  int i = blockIdx.x*blockDim.x + threadIdx.x;
  if (i < n) dst[i] = ldf(src, i, *flag);
}

// ---------------- lens: mask dtype sniffed (u8 / i32 / bf16 / f32) ----------------
__global__ void k_lens(const void* maskp, int* lens){
  int b = blockIdx.x*blockDim.x + threadIdx.x;
  if (b >= B_) return;
  const unsigned char* mc = (const unsigned char*)maskp;
  int mode;
  if (mc[0] == 1 && mc[1] == 1) mode = 0;
  else if (mc[0] == 1)          mode = 1;
  else if (mc[0] == 0x80)       mode = 2;
  else                          mode = 3;
  int cnt = 0;
  for (int j = 0; j < S_; ++j){
    long idx = (long)b*S_ + j; int v;
    if (mode == 0)      v = (mc[idx] != 0);
    else if (mode == 1) v = (((const int*)maskp)[idx] != 0);
    else if (mode == 2) v = (((const unsigned short*)maskp)[idx] != 0);
    else                v = (((const float*)maskp)[idx] > 0.5f);
    cnt += v;
  }
  lens[b] = cnt;
}

// ---------------- one-hot -> token index (dtype-adaptive) ----------------
__global__ void k_ids(const void* ohin, const void* ohout, const int* flag,
                      int* __restrict__ idsIn, int* __restrict__ idsOut){
  int row = blockIdx.x*blockDim.x + threadIdx.x;
  if (row >= B_*S_) return;
  long base = (long)row * V_;
  int isf = *flag;
  int ia = 0, ib = 0;
  if (isf){
    const float* a = (const float*)ohin; const float* c = (const float*)ohout;
    for (int v = 0; v < V_; ++v){
      if (a[base+v] > 0.5f) ia = v;
      if (c[base+v] > 0.5f) ib = v;
    }
  } else {
    const unsigned short* a = (const unsigned short*)ohin;
    const unsigned short* c = (const unsigned short*)ohout;
    for (int v = 0; v < V_; ++v){
      if (a[base+v] >= 0x3F00u) ia = v;
      if (c[base+v] >= 0x3F00u) ib = v;
    }
  }
  idsIn[row] = ia; idsOut[row] = ib;
}

// ---------------- fold embedding + input projection + biases into [V][H] tables ----------------
__global__ void k_tables(const void* W_emb, const void* b_emb,
                         const void* W_ih_e, const void* b_ih_e, const void* b_hh_e,
                         const void* W_ih_d, const void* b_ih_d, const void* b_hh_d,
                         const int* flag,
                         float* __restrict__ encT, float* __restrict__ decT,
                         float* __restrict__ posT){
  int v = blockIdx.x, h = threadIdx.x;
  int isf = *flag;
  float ae = 0.f, ad = 0.f;
  for (int e = 0; e < E_; ++e){
    float x = ldf(W_emb, (long)e*V_ + v, isf) + ldf(b_emb, e, isf);
    ae = fmaf(ldf(W_ih_e, (long)h*(E_+V_) + e, isf), x, ae);
    ad = fmaf(ldf(W_ih_d, (long)h*E_ + e, isf), x, ad);
  }
  encT[v*H_ + h] = ae + ldf(b_ih_e, h, isf) + ldf(b_hh_e, h, isf);
  decT[v*H_ + h] = ad + ldf(b_ih_d, h, isf) + ldf(b_hh_d, h, isf);
  posT[v*H_ + h] = ldf(W_ih_e, (long)h*(E_+V_) + E_ + v, isf);
}

#define FRAG_LIST(F) F(0) F(1) F(2) F(3) F(4) F(5) F(6) F(7) \
                     F(8) F(9) F(10) F(11) F(12) F(13) F(14) F(15)

// 128-dot with XOR-staggered reads; W literal-indexed (wq[0..7]), hp[LIT^q4]
#define MV8(ACC0, ACC1, BP) \
  { float4 u,v; \
    u = (BP)[0^q4]; v = (BP)[1^q4]; \
    ACC0 = fmaf(wq[0].x,u.x,ACC0); ACC0 = fmaf(wq[0].y,u.y,ACC0); \
    ACC0 = fmaf(wq[0].z,u.z,ACC0); ACC0 = fmaf(wq[0].w,u.w,ACC0); \
    ACC1 = fmaf(wq[1].x,v.x,ACC1); ACC1 = fmaf(wq[1].y,v.y,ACC1); \
    ACC1 = fmaf(wq[1].z,v.z,ACC1); ACC1 = fmaf(wq[1].w,v.w,ACC1); \
    u = (BP)[2^q4]; v = (BP)[3^q4]; \
    ACC0 = fmaf(wq[2].x,u.x,ACC0); ACC0 = fmaf(wq[2].y,u.y,ACC0); \
    ACC0 = fmaf(wq[2].z,u.z,ACC0); ACC0 = fmaf(wq[2].w,u.w,ACC0); \
    ACC1 = fmaf(wq[3].x,v.x,ACC1); ACC1 = fmaf(wq[3].y,v.y,ACC1); \
    ACC1 = fmaf(wq[3].z,v.z,ACC1); ACC1 = fmaf(wq[3].w,v.w,ACC1); \
    u = (BP)[4^q4]; v = (BP)[5^q4]; \
    ACC0 = fmaf(wq[4].x,u.x,ACC0); ACC0 = fmaf(wq[4].y,u.y,ACC0); \
    ACC0 = fmaf(wq[4].z,u.z,ACC0); ACC0 = fmaf(wq[4].w,u.w,ACC0); \
    ACC1 = fmaf(wq[5].x,v.x,ACC1); ACC1 = fmaf(wq[5].y,v.y,ACC1); \
    ACC1 = fmaf(wq[5].z,v.z,ACC1); ACC1 = fmaf(wq[5].w,v.w,ACC1); \
    u = (BP)[6^q4]; v = (BP)[7^q4]; \
    ACC0 = fmaf(wq[6].x,u.x,ACC0); ACC0 = fmaf(wq[6].y,u.y,ACC0); \
    ACC0 = fmaf(wq[6].z,u.z,ACC0); ACC0 = fmaf(wq[6].w,u.w,ACC0); \
    ACC1 = fmaf(wq[7].x,v.x,ACC1); ACC1 = fmaf(wq[7].y,v.y,ACC1); \
    ACC1 = fmaf(wq[7].z,v.z,ACC1); ACC1 = fmaf(wq[7].w,v.w,ACC1); }

// ---------------- main serial kernel: one workgroup per batch row, all f32 ----------------
// Enc fragments live in 16 NAMED float4 registers.
// VGPR budget: __launch_bounds__(512, 2) == min 2 BLOCKS/CU (CUDA semantics on this
// toolchain, measured R4/R5/R8-R11) -> 4 waves/SIMD -> 128-VGPR cap. The (512,4) form
// capped at 64 and spilled ~60 regs/thread -> GB-scale scratch traffic (R8-R10).
__global__ __launch_bounds__(NT_, 2) void k_main(
    const int* __restrict__ idsIn, const int* __restrict__ idsOut, const int* __restrict__ lens,
    const float* __restrict__ encT, const float* __restrict__ decT, const float* __restrict__ posT,
    const float* __restrict__ W_hh_e, const float* __restrict__ W_e2d, const float* __restrict__ b_e2d,
    const float* __restrict__ W_hh_d, float* __restrict__ out)
{
  __shared__ __align__(16) float hv0[H_], hv1[H_], nxtF[H_], decF[H_];
  __shared__ __align__(16) float scr[S_];
  __shared__ __align__(16) float4 ctxP4[16*32];
  __shared__ float red[4];

  const int b = blockIdx.x, t = threadIdx.x;
  const int h = t >> 2, q4 = t & 3;      // matvec: 4 threads / output row
  const int hq = t & 31, g = t >> 5;     // fragments: 32 h-quads x 16 s-groups
  const int len = lens[b];

  // out row 0: log(full(EPS).at[:,0].set(1))
  if (t < V_) out[(size_t)b*S_*V_ + t] = (t==0) ? 0.f : -46.051701859880914f;

  // encoder recurrent weights (XOR-staggered, literal-indexed everywhere)
  float4 wq[8];
  #pragma unroll
  for (int r=0;r<8;++r) wq[r] = ((const float4*)W_hh_e)[h*32 + q4*8 + (r^q4)];

  // NAMED enc fragments: cJ = enc[g*16+J][hq*4..hq*4+3]
  #define DECL_C(J) float4 c##J = make_float4(0.f,0.f,0.f,0.f);
  FRAG_LIST(DECL_C)
  #undef DECL_C

  if (t < H_){ hv0[t]=0.f; hv1[t]=0.f; }
  __syncthreads();

  // -------- encoder: dynamic grp loop x 16 macro-expanded steps; named captures --------
  const int* idsInB = idsIn + b*S_;
  int cur = 0;
  for (int grp = 0; grp < 16; ++grp){
    #define ENCSTEP(J) { \
      const int st = grp*16 + (J); \
      if (st < len){ \
        const float* hvc = cur ? hv1 : hv0; \
        float* hvn = cur ? hv0 : hv1; \
        const float4* hp = (const float4*)(hvc + q4*32); \
        float a0=0.f, a1=0.f; \
        MV8(a0, a1, hp) \
        float acc = a0 + a1; \
        acc += __shfl_xor(acc,1); acc += __shfl_xor(acc,2); \
        if (q4==0){ \
          float pre = acc + encT[idsInB[st]*H_ + h]; \
          if (st < V_) pre += posT[st*H_ + h]; \
          hvn[h] = tanhf(pre); \
        } \
        __syncthreads(); \
        cur ^= 1; \
      } \
      if (g == grp) c##J = ((const float4*)(cur ? hv1 : hv0))[hq]; \
    }
    FRAG_LIST(ENCSTEP)
    #undef ENCSTEP
  }
  const float* hvF = cur ? hv1 : hv0;

  // decoder recurrent weights overwrite wq (encoder weights dead)
  #pragma unroll
  for (int r=0;r<8;++r) wq[r] = ((const float4*)W_hh_d)[h*32 + q4*8 + (r^q4)];

  const int* idsOutB = idsOut + b*S_;

  // -------- decode loop (reference order; logits deferred to k_logits) --------
  for (int k=0; k<S_; ++k){
    // ---- P1: nxt ----
    if (k == 0){
      const float4* hp  = (const float4*)(hvF + q4*32);
      const float4* We4 = (const float4*)W_e2d + h*32 + q4*8;
      float a = 0.f;
      #pragma unroll
      for (int r=0;r<8;++r){ float4 u = hp[r]; float4 w = We4[r];
        a = fmaf(w.x,u.x,a); a = fmaf(w.y,u.y,a);
        a = fmaf(w.z,u.z,a); a = fmaf(w.w,u.w,a); }
      a += __shfl_xor(a,1); a += __shfl_xor(a,2);
      if (q4==0) nxtF[h] = a + b_e2d[h];
    } else {
      int id = idsOutB[k-1];
      const float4* dp = (const float4*)decF + q4*8;
      float a0=0.f, a1=0.f;
      MV8(a0, a1, dp)
      float acc = a0 + a1;
      acc += __shfl_xor(acc,1); acc += __shfl_xor(acc,2);
      if (q4==0) nxtF[h] = tanhf(acc + decT[id*H_ + h]);
    }
    __syncthreads();

    // ---- P2: scores, fully scalarized partials + half-wave reduce-scatter ----
    {
      float4 nx = ((const float4*)nxtF)[hq];
      #define DOTP(J) float p##J = fmaf(c##J.w,nx.w, fmaf(c##J.z,nx.z, \
                        fmaf(c##J.y,nx.y, c##J.x*nx.x)));
      FRAG_LIST(DOTP)
      #undef DOTP
      const int s1 = (hq>>4)&1, s2=(hq>>3)&1, s3=(hq>>2)&1, s4=(hq>>1)&1;
      float x0 = (s1? p8  : p0) + __shfl_xor(s1? p0 : p8 , 16);
      float x1 = (s1? p9  : p1) + __shfl_xor(s1? p1 : p9 , 16);
      float x2 = (s1? p10 : p2) + __shfl_xor(s1? p2 : p10, 16);
      float x3 = (s1? p11 : p3) + __shfl_xor(s1? p3 : p11, 16);
      float x4 = (s1? p12 : p4) + __shfl_xor(s1? p4 : p12, 16);
      float x5 = (s1? p13 : p5) + __shfl_xor(s1? p5 : p13, 16);
      float x6 = (s1? p14 : p6) + __shfl_xor(s1? p6 : p14, 16);
      float x7 = (s1? p15 : p7) + __shfl_xor(s1? p7 : p15, 16);
      float y0 = (s2? x4 : x0) + __shfl_xor(s2? x0 : x4, 8);
      float y1 = (s2? x5 : x1) + __shfl_xor(s2? x1 : x5, 8);
      float y2 = (s2? x6 : x2) + __shfl_xor(s2? x2 : x6, 8);
      float y3 = (s2? x7 : x3) + __shfl_xor(s2? x3 : x7, 8);
      float z0 = (s3? y2 : y0) + __shfl_xor(s3? y0 : y2, 4);
      float z1 = (s3? y3 : y1) + __shfl_xor(s3? y1 : y3, 4);
      float w0 = (s4? z1 : z0) + __shfl_xor(s4? z0 : z1, 2);
      w0 += __shfl_xor(w0, 1);
      if ((hq & 1) == 0){
        int j = s1*8 + s2*4 + s3*2 + s4;
        scr[g*16 + j] = w0;
      }
    }
    __syncthreads();

    // ---- P3: wave0 masked softmax ----
    if (t < 64){
      float v0 = scr[t];                                   // len>=64 -> always valid
      float v1 = (t+64  < len)? scr[t+64]  : -1e30f;
      float v2 = (t+128 < len)? scr[t+128] : -1e30f;
      float v3 = (t+192 < len)? scr[t+192] : -1e30f;
      float m = fmaxf(fmaxf(v0,v1), fmaxf(v2,v3));
      #pragma unroll
      for (int o=1;o<64;o<<=1) m = fmaxf(m, __shfl_xor(m,o));
      float e0 = expf(v0-m);
      float e1 = (t+64  < len)? expf(v1-m) : 0.f;
      float e2 = (t+128 < len)? expf(v2-m) : 0.f;
      float e3 = (t+192 < len)? expf(v3-m) : 0.f;
      scr[t]=e0; scr[t+64]=e1; scr[t+128]=e2; scr[t+192]=e3;
      float ss = (e0+e1)+(e2+e3);
      #pragma unroll
      for (int o=1;o<64;o<<=1) ss += __shfl_xor(ss,o);
      if (t==0) red[0] = 1.f/ss;
    }
    __syncthreads();

    // ---- P4: ctx partials (broadcast weight reads, named register fragments) ----
    {
      const float4* wp = (const float4*)scr + g*4;
      float4 wa = wp[0], wb = wp[1], wc = wp[2], we = wp[3];
      float4 ca = make_float4(0.f,0.f,0.f,0.f);
      #define CADD2(S, C) { ca.x=fmaf((S),C.x,ca.x); ca.y=fmaf((S),C.y,ca.y); \
                            ca.z=fmaf((S),C.z,ca.z); ca.w=fmaf((S),C.w,ca.w); }
      CADD2(wa.x,c0)  CADD2(wa.y,c1)  CADD2(wa.z,c2)  CADD2(wa.w,c3)
      CADD2(wb.x,c4)  CADD2(wb.y,c5)  CADD2(wb.z,c6)  CADD2(wb.w,c7)
      CADD2(wc.x,c8)  CADD2(wc.y,c9)  CADD2(wc.z,c10) CADD2(wc.w,c11)
      CADD2(we.x,c12) CADD2(we.y,c13) CADD2(we.z,c14) CADD2(we.w,c15)
      #undef CADD2
      ctxP4[g*32 + ((hq + g) & 31)] = ca;
    }
    __syncthreads();

    // ---- P5: reduce partials; dec = nxt + ctx/Z; store dec_k to out row k ----
    if (t < 32){
      float4 cs = make_float4(0.f,0.f,0.f,0.f);
      #pragma unroll
      for (int g2=0; g2<16; ++g2){
        float4 p4 = ctxP4[g2*32 + ((t + g2) & 31)];
        cs.x+=p4.x; cs.y+=p4.y; cs.z+=p4.z; cs.w+=p4.w;
      }
      float inv = red[0];
      float4 nx = ((const float4*)nxtF)[t];
      float4 d = make_float4(nx.x + cs.x*inv, nx.y + cs.y*inv,
                             nx.z + cs.z*inv, nx.w + cs.w*inv);
      ((float4*)decF)[t] = d;
      if (k > 0) *((float4*)(out + ((size_t)b*S_ + k)*V_) + t) = d;
    }
    __syncthreads();
  }
}

// ---------------- pass 2: in-place logits + log-softmax over out rows 1..255 ----------------
__global__ __launch_bounds__(256) void k_logits(const float* __restrict__ Wo,
                                                const float* __restrict__ bo,
                                                float* __restrict__ out)
{
  const int b = blockIdx.x, t = threadIdx.x;
  const int v = t >> 1, half = t & 1;
  const int wid = t >> 6, lane = t & 63;
  __shared__ float xch[8];
  float4 wo4[16];
  #pragma unroll
  for (int r=0;r<16;++r) wo4[r] = ((const float4*)Wo)[v*32 + half*16 + r];
  const float bov = bo[v];

  for (int k = 1 + blockIdx.y; k < S_; k += 8){
    float* rowp = out + ((size_t)b*S_ + k)*V_;
    const float4* dr = (const float4*)rowp + half*16;
    float acc = 0.f;
    #pragma unroll
    for (int r=0;r<16;++r){
      float4 d = dr[r];
      acc = fmaf(wo4[r].x,d.x,acc); acc = fmaf(wo4[r].y,d.y,acc);
      acc = fmaf(wo4[r].z,d.z,acc); acc = fmaf(wo4[r].w,d.w,acc);
    }
    acc += __shfl_xor(acc, 1);          // both half-threads now hold the full dot
    float logit = acc + bov;
    float m = logit;
    #pragma unroll
    for (int o=1;o<64;o<<=1) m = fmaxf(m, __shfl_xor(m,o));
    if (lane==0) xch[wid] = m;
    __syncthreads();
    float M = fmaxf(fmaxf(xch[0],xch[1]), fmaxf(xch[2],xch[3]));
    float e = (half==0) ? expf(logit - M) : 0.f;   // count each v once
    float s = e;
    #pragma unroll
    for (int o=1;o<64;o<<=1) s += __shfl_xor(s,o);
    if (lane==0) xch[4+wid] = s;
    __syncthreads();
    float Ss = (xch[4]+xch[5]) + (xch[6]+xch[7]);
    if (half==0) rowp[v] = logit - M - logf(Ss);
    __syncthreads();   // protect xch[0..3] of next iteration
  }
}

extern "C" void kernel_launch(void* const* d_in, const int* in_sizes, int n_in,
                              void* d_out, int out_size, void* d_ws, size_t ws_size,
                              hipStream_t stream)
{
  const void* ohin   = d_in[0];
  const void* ohout  = d_in[1];
  const void* maskp  = d_in[2];
  const void* W_emb  = d_in[3];
  const void* b_emb  = d_in[4];
  const void* W_ih_e = d_in[5];
  const void* W_hh_e = d_in[6];
  const void* b_ih_e = d_in[7];
  const void* b_hh_e = d_in[8];
  const void* W_e2d  = d_in[9];
  const void* b_e2d  = d_in[10];
  const void* W_ih_d = d_in[11];
  const void* W_hh_d = d_in[12];
  const void* b_ih_d = d_in[13];
  const void* b_hh_d = d_in[14];
  const void* W_out  = d_in[15];
  const void* b_out  = d_in[16];
  float* out = (float*)d_out;

  char* ws = (char*)d_ws;
  int* idsIn   = (int*)ws;   ws += (size_t)B_*S_*sizeof(int);
  int* idsOut  = (int*)ws;   ws += (size_t)B_*S_*sizeof(int);
  int* lens    = (int*)ws;   ws += 2048;
  int* flag    = (int*)ws;   ws += 1024;
  float* encT  = (float*)ws; ws += (size_t)V_*H_*sizeof(float);
  float* decT  = (float*)ws; ws += (size_t)V_*H_*sizeof(float);
  float* posT  = (float*)ws; ws += (size_t)V_*H_*sizeof(float);
  float* WheF  = (float*)ws; ws += (size_t)H_*H_*sizeof(float);
  float* WddF  = (float*)ws; ws += (size_t)H_*H_*sizeof(float);
  float* WooF  = (float*)ws; ws += (size_t)H_*H_*sizeof(float);
  float* WedF  = (float*)ws; ws += (size_t)H_*H_*sizeof(float);
  float* be2dF = (float*)ws; ws += 512;
  float* boutF = (float*)ws; ws += 512;

  k_sniff<<<1, 64, 0, stream>>>((const unsigned short*)ohin, flag);
  k_lens<<<2, 256, 0, stream>>>(maskp, lens);
  k_ids<<<(B_*S_)/256, 256, 0, stream>>>(ohin, ohout, flag, idsIn, idsOut);
  k_tables<<<V_, H_, 0, stream>>>(W_emb, b_emb, W_ih_e, b_ih_e, b_hh_e,
                                  W_ih_d, b_ih_d, b_hh_d, flag, encT, decT, posT);
  k_cvt<<<(H_*H_+255)/256, 256, 0, stream>>>(W_hh_e, WheF, H_*H_, flag);
  k_cvt<<<(H_*H_+255)/256, 256, 0, stream>>>(W_hh_d, WddF, H_*H_, flag);
  k_cvt<<<(H_*H_+255)/256, 256, 0, stream>>>(W_out,  WooF, H_*H_, flag);
  k_cvt<<<(H_*H_+255)/256, 256, 0, stream>>>(W_e2d,  WedF, H_*H_, flag);
  k_cvt<<<1, 128, 0, stream>>>(b_e2d, be2dF, H_, flag);
  k_cvt<<<1, 128, 0, stream>>>(b_out, boutF, H_, flag);

  k_main<<<B_, NT_, 0, stream>>>(idsIn, idsOut, lens, encT, decT, posT,
                                 WheF, WedF, be2dF, WddF, out);

  dim3 gl(B_, 8);
  k_logits<<<gl, 256, 0, stream>>>(WooF, boutF, out);
}

// Round 13
// 1747.181 us; speedup vs baseline: 1.9911x; 1.2037x over previous
//
#include <hip/hip_runtime.h>

#define B_ 512
#define S_ 256
#define V_ 128
#define E_ 64
#define H_ 128
#define NT_ 512

// ---------------- dtype sniff: first 512 bytes of one_hot_inputs ----------------
// f32: 512B = row 0 (one 1.0f) -> 1 nonzero u16; bf16: rows 0+1 -> 2 nonzero u16
__global__ void k_sniff(const unsigned short* oh, int* flag){
  if (threadIdx.x == 0){
    int cnt = 0;
    for (int i = 0; i < 256; ++i) cnt += (oh[i] != 0);
    *flag = (cnt == 1) ? 1 : 0;
  }
}

__device__ __forceinline__ float ldf(const void* p, long i, int isf){
  if (isf) return ((const float*)p)[i];
  unsigned v = ((const unsigned short*)p)[i];
  union{unsigned u; float f;} c; c.u = v << 16; return c.f;
}

// ---------------- 4-matrix convert-to-f32 (one launch) ----------------
__global__ void k_cvt4(const void* s0, const void* s1, const void* s2, const void* s3,
                       float* d0, float* d1, float* d2, float* d3, const int* flag){
  int i = blockIdx.x*blockDim.x + threadIdx.x;
  if (i >= H_*H_) return;
  int w = blockIdx.y;
  const void* s = (w==0)? s0 : (w==1)? s1 : (w==2)? s2 : s3;
  float* d      = (w==0)? d0 : (w==1)? d1 : (w==2)? d2 : d3;
  d[i] = ldf(s, i, *flag);
}

// ---------------- lens: mask dtype sniffed (u8 / i32 / bf16 / f32) ----------------
__global__ void k_lens(const void* maskp, int* lens){
  int b = blockIdx.x*blockDim.x + threadIdx.x;
  if (b >= B_) return;
  const unsigned char* mc = (const unsigned char*)maskp;
  int mode;
  if (mc[0] == 1 && mc[1] == 1) mode = 0;
  else if (mc[0] == 1)          mode = 1;
  else if (mc[0] == 0x80)       mode = 2;
  else                          mode = 3;
  int cnt = 0;
  for (int j = 0; j < S_; ++j){
    long idx = (long)b*S_ + j; int v;
    if (mode == 0)      v = (mc[idx] != 0);
    else if (mode == 1) v = (((const int*)maskp)[idx] != 0);
    else if (mode == 2) v = (((const unsigned short*)maskp)[idx] != 0);
    else                v = (((const float*)maskp)[idx] > 0.5f);
    cnt += v;
  }
  lens[b] = cnt;
}

// ---------------- one-hot -> token index: ballot, 4 rows / 256-thr block ----------------
__global__ void k_ids(const void* ohin, const void* ohout, const int* flag,
                      int* __restrict__ idsIn, int* __restrict__ idsOut){
  int row = blockIdx.x*4 + (threadIdx.x >> 6);
  int l = threadIdx.x & 63;
  long base = (long)row * V_;
  int isf = *flag;
  bool a0,a1,b0,b1;
  if (isf){
    const float* a = (const float*)ohin; const float* c = (const float*)ohout;
    a0 = a[base+l]    > 0.5f; a1 = a[base+64+l] > 0.5f;
    b0 = c[base+l]    > 0.5f; b1 = c[base+64+l] > 0.5f;
  } else {
    const unsigned short* a = (const unsigned short*)ohin;
    const unsigned short* c = (const unsigned short*)ohout;
    a0 = a[base+l]    >= 0x3F00u; a1 = a[base+64+l] >= 0x3F00u;
    b0 = c[base+l]    >= 0x3F00u; b1 = c[base+64+l] >= 0x3F00u;
  }
  unsigned long long ma = __ballot(a0), mb = __ballot(a1);
  unsigned long long mc = __ballot(b0), md = __ballot(b1);
  if (l == 0){
    idsIn[row]  = ma ? (int)__builtin_ctzll(ma) : 64 + (int)__builtin_ctzll(mb);
    idsOut[row] = mc ? (int)__builtin_ctzll(mc) : 64 + (int)__builtin_ctzll(md);
  }
}

// ---------------- tables + bias conversion (fused) ----------------
__global__ void k_tables(const void* W_emb, const void* b_emb,
                         const void* W_ih_e, const void* b_ih_e, const void* b_hh_e,
                         const void* W_ih_d, const void* b_ih_d, const void* b_hh_d,
                         const void* b_e2d, const void* b_out, const int* flag,
                         float* __restrict__ encT, float* __restrict__ decT,
                         float* __restrict__ posT,
                         float* __restrict__ be2dF, float* __restrict__ boutF){
  int v = blockIdx.x, h = threadIdx.x;
  int isf = *flag;
  float ae = 0.f, ad = 0.f;
  for (int e = 0; e < E_; ++e){
    float x = ldf(W_emb, (long)e*V_ + v, isf) + ldf(b_emb, e, isf);
    ae = fmaf(ldf(W_ih_e, (long)h*(E_+V_) + e, isf), x, ae);
    ad = fmaf(ldf(W_ih_d, (long)h*E_ + e, isf), x, ad);
  }
  encT[v*H_ + h] = ae + ldf(b_ih_e, h, isf) + ldf(b_hh_e, h, isf);
  decT[v*H_ + h] = ad + ldf(b_ih_d, h, isf) + ldf(b_hh_d, h, isf);
  posT[v*H_ + h] = ldf(W_ih_e, (long)h*(E_+V_) + E_ + v, isf);
  if (v == 0){ be2dF[h] = ldf(b_e2d, h, isf); boutF[h] = ldf(b_out, h, isf); }
}

#define FRAG_LIST(F) F(0) F(1) F(2) F(3) F(4) F(5) F(6) F(7) \
                     F(8) F(9) F(10) F(11) F(12) F(13) F(14) F(15)

// 128-dot with XOR-staggered reads; W literal-indexed (wq[0..7]), hp[LIT^q4]
#define MV8(ACC0, ACC1, BP) \
  { float4 u,v; \
    u = (BP)[0^q4]; v = (BP)[1^q4]; \
    ACC0 = fmaf(wq[0].x,u.x,ACC0); ACC0 = fmaf(wq[0].y,u.y,ACC0); \
    ACC0 = fmaf(wq[0].z,u.z,ACC0); ACC0 = fmaf(wq[0].w,u.w,ACC0); \
    ACC1 = fmaf(wq[1].x,v.x,ACC1); ACC1 = fmaf(wq[1].y,v.y,ACC1); \
    ACC1 = fmaf(wq[1].z,v.z,ACC1); ACC1 = fmaf(wq[1].w,v.w,ACC1); \
    u = (BP)[2^q4]; v = (BP)[3^q4]; \
    ACC0 = fmaf(wq[2].x,u.x,ACC0); ACC0 = fmaf(wq[2].y,u.y,ACC0); \
    ACC0 = fmaf(wq[2].z,u.z,ACC0); ACC0 = fmaf(wq[2].w,u.w,ACC0); \
    ACC1 = fmaf(wq[3].x,v.x,ACC1); ACC1 = fmaf(wq[3].y,v.y,ACC1); \
    ACC1 = fmaf(wq[3].z,v.z,ACC1); ACC1 = fmaf(wq[3].w,v.w,ACC1); \
    u = (BP)[4^q4]; v = (BP)[5^q4]; \
    ACC0 = fmaf(wq[4].x,u.x,ACC0); ACC0 = fmaf(wq[4].y,u.y,ACC0); \
    ACC0 = fmaf(wq[4].z,u.z,ACC0); ACC0 = fmaf(wq[4].w,u.w,ACC0); \
    ACC1 = fmaf(wq[5].x,v.x,ACC1); ACC1 = fmaf(wq[5].y,v.y,ACC1); \
    ACC1 = fmaf(wq[5].z,v.z,ACC1); ACC1 = fmaf(wq[5].w,v.w,ACC1); \
    u = (BP)[6^q4]; v = (BP)[7^q4]; \
    ACC0 = fmaf(wq[6].x,u.x,ACC0); ACC0 = fmaf(wq[6].y,u.y,ACC0); \
    ACC0 = fmaf(wq[6].z,u.z,ACC0); ACC0 = fmaf(wq[6].w,u.w,ACC0); \
    ACC1 = fmaf(wq[7].x,v.x,ACC1); ACC1 = fmaf(wq[7].y,v.y,ACC1); \
    ACC1 = fmaf(wq[7].z,v.z,ACC1); ACC1 = fmaf(wq[7].w,v.w,ACC1); }

// ---------------- main serial kernel: one workgroup per batch row, all f32 ----------------
// __launch_bounds__(512, 2): measured VGPR cap 128 on this toolchain (R5/R12);
// the (512,4) form caps at 64 and spills ~60 regs/thread (R8-R10 regression).
__global__ __launch_bounds__(NT_, 2) void k_main(
    const int* __restrict__ idsIn, const int* __restrict__ idsOut, const int* __restrict__ lens,
    const float* __restrict__ encT, const float* __restrict__ decT, const float* __restrict__ posT,
    const float* __restrict__ W_hh_e, const float* __restrict__ W_e2d, const float* __restrict__ b_e2d,
    const float* __restrict__ W_hh_d, float* __restrict__ out)
{
  __shared__ __align__(16) float hv0[H_], hv1[H_], nxtF[H_], decF[H_];
  __shared__ __align__(16) float scr[S_];
  __shared__ __align__(16) float4 ctxP4[16*32];
  __shared__ float red[4];

  const int b = blockIdx.x, t = threadIdx.x;
  const int h = t >> 2, q4 = t & 3;      // matvec: 4 threads / output row
  const int hq = t & 31, g = t >> 5;     // fragments: 32 h-quads x 16 s-groups
  const int len = lens[b];

  // out row 0: log(full(EPS).at[:,0].set(1))
  if (t < V_) out[(size_t)b*S_*V_ + t] = (t==0) ? 0.f : -46.051701859880914f;

  // encoder recurrent weights (XOR-staggered, literal-indexed everywhere)
  float4 wq[8];
  #pragma unroll
  for (int r=0;r<8;++r) wq[r] = ((const float4*)W_hh_e)[h*32 + q4*8 + (r^q4)];

  // NAMED enc fragments: cJ = enc[g*16+J][hq*4..hq*4+3]
  #define DECL_C(J) float4 c##J = make_float4(0.f,0.f,0.f,0.f);
  FRAG_LIST(DECL_C)
  #undef DECL_C

  if (t < H_){ hv0[t]=0.f; hv1[t]=0.f; }
  __syncthreads();

  // -------- encoder: dynamic grp loop x 16 macro-expanded steps; named captures --------
  const int* idsInB = idsIn + b*S_;
  int cur = 0;
  for (int grp = 0; grp < 16; ++grp){
    #define ENCSTEP(J) { \
      const int st = grp*16 + (J); \
      if (st < len){ \
        const float* hvc = cur ? hv1 : hv0; \
        float* hvn = cur ? hv0 : hv1; \
        const float4* hp = (const float4*)(hvc + q4*32); \
        float a0=0.f, a1=0.f; \
        MV8(a0, a1, hp) \
        float acc = a0 + a1; \
        acc += __shfl_xor(acc,1); acc += __shfl_xor(acc,2); \
        if (q4==0){ \
          float pre = acc + encT[idsInB[st]*H_ + h]; \
          if (st < V_) pre += posT[st*H_ + h]; \
          hvn[h] = tanhf(pre); \
        } \
        __syncthreads(); \
        cur ^= 1; \
      } \
      if (g == grp) c##J = ((const float4*)(cur ? hv1 : hv0))[hq]; \
    }
    FRAG_LIST(ENCSTEP)
    #undef ENCSTEP
  }
  const float* hvF = cur ? hv1 : hv0;

  // decoder recurrent weights overwrite wq (encoder weights dead)
  #pragma unroll
  for (int r=0;r<8;++r) wq[r] = ((const float4*)W_hh_d)[h*32 + q4*8 + (r^q4)];

  const int* idsOutB = idsOut + b*S_;

  // prefetch decT row for k=1 (ids are static -> fully hoistable)
  float dpre = decT[idsOutB[0]*H_ + h];

  // -------- decode loop (reference order; logits deferred to k_logits) --------
  for (int k=0; k<S_; ++k){
    // ---- P1: nxt ----
    if (k == 0){
      const float4* hp  = (const float4*)(hvF + q4*32);
      const float4* We4 = (const float4*)W_e2d + h*32 + q4*8;
      float a = 0.f;
      #pragma unroll
      for (int r=0;r<8;++r){ float4 u = hp[r]; float4 w = We4[r];
        a = fmaf(w.x,u.x,a); a = fmaf(w.y,u.y,a);
        a = fmaf(w.z,u.z,a); a = fmaf(w.w,u.w,a); }
      a += __shfl_xor(a,1); a += __shfl_xor(a,2);
      if (q4==0) nxtF[h] = a + b_e2d[h];
    } else {
      const float4* dp = (const float4*)decF + q4*8;
      float a0=0.f, a1=0.f;
      MV8(a0, a1, dp)
      float acc = a0 + a1;
      acc += __shfl_xor(acc,1); acc += __shfl_xor(acc,2);
      if (q4==0) nxtF[h] = tanhf(acc + dpre);
    }
    // prefetch decT row for iteration k+1 (uses idsOutB[k]); hidden under P2-P5
    if (k < S_-1) dpre = decT[idsOutB[k]*H_ + h];
    __syncthreads();

    // ---- P2: scores, fully scalarized partials + half-wave reduce-scatter ----
    {
      float4 nx = ((const float4*)nxtF)[hq];
      #define DOTP(J) float p##J = fmaf(c##J.w,nx.w, fmaf(c##J.z,nx.z, \
                        fmaf(c##J.y,nx.y, c##J.x*nx.x)));
      FRAG_LIST(DOTP)
      #undef DOTP
      const int s1 = (hq>>4)&1, s2=(hq>>3)&1, s3=(hq>>2)&1, s4=(hq>>1)&1;
      float x0 = (s1? p8  : p0) + __shfl_xor(s1? p0 : p8 , 16);
      float x1 = (s1? p9  : p1) + __shfl_xor(s1? p1 : p9 , 16);
      float x2 = (s1? p10 : p2) + __shfl_xor(s1? p2 : p10, 16);
      float x3 = (s1? p11 : p3) + __shfl_xor(s1? p3 : p11, 16);
      float x4 = (s1? p12 : p4) + __shfl_xor(s1? p4 : p12, 16);
      float x5 = (s1? p13 : p5) + __shfl_xor(s1? p5 : p13, 16);
      float x6 = (s1? p14 : p6) + __shfl_xor(s1? p6 : p14, 16);
      float x7 = (s1? p15 : p7) + __shfl_xor(s1? p7 : p15, 16);
      float y0 = (s2? x4 : x0) + __shfl_xor(s2? x0 : x4, 8);
      float y1 = (s2? x5 : x1) + __shfl_xor(s2? x1 : x5, 8);
      float y2 = (s2? x6 : x2) + __shfl_xor(s2? x2 : x6, 8);
      float y3 = (s2? x7 : x3) + __shfl_xor(s2? x3 : x7, 8);
      float z0 = (s3? y2 : y0) + __shfl_xor(s3? y0 : y2, 4);
      float z1 = (s3? y3 : y1) + __shfl_xor(s3? y1 : y3, 4);
      float w0 = (s4? z1 : z0) + __shfl_xor(s4? z0 : z1, 2);
      w0 += __shfl_xor(w0, 1);
      if ((hq & 1) == 0){
        int j = s1*8 + s2*4 + s3*2 + s4;
        scr[g*16 + j] = w0;
      }
    }
    __syncthreads();

    // ---- P3: wave0 masked softmax ----
    if (t < 64){
      float v0 = scr[t];                                   // len>=64 -> always valid
      float v1 = (t+64  < len)? scr[t+64]  : -1e30f;
      float v2 = (t+128 < len)? scr[t+128] : -1e30f;
      float v3 = (t+192 < len)? scr[t+192] : -1e30f;
      float m = fmaxf(fmaxf(v0,v1), fmaxf(v2,v3));
      #pragma unroll
      for (int o=1;o<64;o<<=1) m = fmaxf(m, __shfl_xor(m,o));
      float e0 = expf(v0-m);
      float e1 = (t+64  < len)? expf(v1-m) : 0.f;
      float e2 = (t+128 < len)? expf(v2-m) : 0.f;
      float e3 = (t+192 < len)? expf(v3-m) : 0.f;
      scr[t]=e0; scr[t+64]=e1; scr[t+128]=e2; scr[t+192]=e3;
      float ss = (e0+e1)+(e2+e3);
      #pragma unroll
      for (int o=1;o<64;o<<=1) ss += __shfl_xor(ss,o);
      if (t==0) red[0] = 1.f/ss;
    }
    __syncthreads();

    // ---- P4: ctx partials (broadcast weight reads, named register fragments) ----
    {
      const float4* wp = (const float4*)scr + g*4;
      float4 wa = wp[0], wb = wp[1], wc = wp[2], we = wp[3];
      float4 ca = make_float4(0.f,0.f,0.f,0.f);
      #define CADD2(S, C) { ca.x=fmaf((S),C.x,ca.x); ca.y=fmaf((S),C.y,ca.y); \
                            ca.z=fmaf((S),C.z,ca.z); ca.w=fmaf((S),C.w,ca.w); }
      CADD2(wa.x,c0)  CADD2(wa.y,c1)  CADD2(wa.z,c2)  CADD2(wa.w,c3)
      CADD2(wb.x,c4)  CADD2(wb.y,c5)  CADD2(wb.z,c6)  CADD2(wb.w,c7)
      CADD2(wc.x,c8)  CADD2(wc.y,c9)  CADD2(wc.z,c10) CADD2(wc.w,c11)
      CADD2(we.x,c12) CADD2(we.y,c13) CADD2(we.z,c14) CADD2(we.w,c15)
      #undef CADD2
      ctxP4[g*32 + ((hq + g) & 31)] = ca;
    }
    __syncthreads();

    // ---- P5: reduce partials; dec = nxt + ctx/Z; store dec_k to out row k ----
    if (t < 32){
      float4 cs = make_float4(0.f,0.f,0.f,0.f);
      #pragma unroll
      for (int g2=0; g2<16; ++g2){
        float4 p4 = ctxP4[g2*32 + ((t + g2) & 31)];
        cs.x+=p4.x; cs.y+=p4.y; cs.z+=p4.z; cs.w+=p4.w;
      }
      float inv = red[0];
      float4 nx = ((const float4*)nxtF)[t];
      float4 d = make_float4(nx.x + cs.x*inv, nx.y + cs.y*inv,
                             nx.z + cs.z*inv, nx.w + cs.w*inv);
      ((float4*)decF)[t] = d;
      if (k > 0) *((float4*)(out + ((size_t)b*S_ + k)*V_) + t) = d;
    }
    __syncthreads();
  }
}

// ---------------- pass 2: in-place logits + log-softmax over out rows 1..255 ----------------
// dec row staged in LDS once per row (was: per-thread global reads -> ~8 GB L2 traffic).
__global__ __launch_bounds__(256) void k_logits(const float* __restrict__ Wo,
                                                const float* __restrict__ bo,
                                                float* __restrict__ out)
{
  const int b = blockIdx.x, t = threadIdx.x;
  const int v = t >> 1, half = t & 1;
  const int wid = t >> 6, lane = t & 63;
  __shared__ __align__(16) float decS[V_];
  __shared__ float xch[8];
  float4 wo4[16];
  #pragma unroll
  for (int r=0;r<16;++r) wo4[r] = ((const float4*)Wo)[v*32 + half*16 + r];
  const float bov = bo[v];

  for (int k = 1 + blockIdx.y; k < S_; k += 8){
    float* rowp = out + ((size_t)b*S_ + k)*V_;
    if (t < V_) decS[t] = rowp[t];
    __syncthreads();
    const float4* dr = (const float4*)decS + half*16;
    float acc = 0.f;
    #pragma unroll
    for (int r=0;r<16;++r){
      float4 d = dr[r];
      acc = fmaf(wo4[r].x,d.x,acc); acc = fmaf(wo4[r].y,d.y,acc);
      acc = fmaf(wo4[r].z,d.z,acc); acc = fmaf(wo4[r].w,d.w,acc);
    }
    acc += __shfl_xor(acc, 1);          // both half-threads now hold the full dot
    float logit = acc + bov;
    float m = logit;
    #pragma unroll
    for (int o=1;o<64;o<<=1) m = fmaxf(m, __shfl_xor(m,o));
    if (lane==0) xch[wid] = m;
    __syncthreads();
    float M = fmaxf(fmaxf(xch[0],xch[1]), fmaxf(xch[2],xch[3]));
    float e = (half==0) ? expf(logit - M) : 0.f;   // count each v once
    float s = e;
    #pragma unroll
    for (int o=1;o<64;o<<=1) s += __shfl_xor(s,o);
    if (lane==0) xch[4+wid] = s;
    __syncthreads();
    float Ss = (xch[4]+xch[5]) + (xch[6]+xch[7]);
    if (half==0) rowp[v] = logit - M - logf(Ss);
    __syncthreads();   // protect decS/xch for next iteration
  }
}

extern "C" void kernel_launch(void* const* d_in, const int* in_sizes, int n_in,
                              void* d_out, int out_size, void* d_ws, size_t ws_size,
                              hipStream_t stream)
{
  const void* ohin   = d_in[0];
  const void* ohout  = d_in[1];
  const void* maskp  = d_in[2];
  const void* W_emb  = d_in[3];
  const void* b_emb  = d_in[4];
  const void* W_ih_e = d_in[5];
  const void* W_hh_e = d_in[6];
  const void* b_ih_e = d_in[7];
  const void* b_hh_e = d_in[8];
  const void* W_e2d  = d_in[9];
  const void* b_e2d  = d_in[10];
  const void* W_ih_d = d_in[11];
  const void* W_hh_d = d_in[12];
  const void* b_ih_d = d_in[13];
  const void* b_hh_d = d_in[14];
  const void* W_out  = d_in[15];
  const void* b_out  = d_in[16];
  float* out = (float*)d_out;

  char* ws = (char*)d_ws;
  int* idsIn   = (int*)ws;   ws += (size_t)B_*S_*sizeof(int);
  int* idsOut  = (int*)ws;   ws += (size_t)B_*S_*sizeof(int);
  int* lens    = (int*)ws;   ws += 2048;
  int* flag    = (int*)ws;   ws += 1024;
  float* encT  = (float*)ws; ws += (size_t)V_*H_*sizeof(float);
  float* decT  = (float*)ws; ws += (size_t)V_*H_*sizeof(float);
  float* posT  = (float*)ws; ws += (size_t)V_*H_*sizeof(float);
  float* WheF  = (float*)ws; ws += (size_t)H_*H_*sizeof(float);
  float* WddF  = (float*)ws; ws += (size_t)H_*H_*sizeof(float);
  float* WooF  = (float*)ws; ws += (size_t)H_*H_*sizeof(float);
  float* WedF  = (float*)ws; ws += (size_t)H_*H_*sizeof(float);
  float* be2dF = (float*)ws; ws += 512;
  float* boutF = (float*)ws; ws += 512;

  k_sniff<<<1, 64, 0, stream>>>((const unsigned short*)ohin, flag);
  k_lens<<<2, 256, 0, stream>>>(maskp, lens);
  k_ids<<<(B_*S_)/4, 256, 0, stream>>>(ohin, ohout, flag, idsIn, idsOut);
  k_tables<<<V_, H_, 0, stream>>>(W_emb, b_emb, W_ih_e, b_ih_e, b_hh_e,
                                  W_ih_d, b_ih_d, b_hh_d, b_e2d, b_out, flag,
                                  encT, decT, posT, be2dF, boutF);
  { dim3 gc((H_*H_+255)/256, 4);
    k_cvt4<<<gc, 256, 0, stream>>>(W_hh_e, W_hh_d, W_out, W_e2d,
                                   WheF, WddF, WooF, WedF, flag); }

  k_main<<<B_, NT_, 0, stream>>>(idsIn, idsOut, lens, encT, decT, posT,
                                 WheF, WedF, be2dF, WddF, out);

  dim3 gl(B_, 8);
  k_logits<<<gl, 256, 0, stream>>>(WooF, boutF, out);
}